// Round 15
// baseline (4123.198 us; speedup 1.0000x reference)
//
#include <hip/hip_runtime.h>

// TrajectoryDecoder: 2-layer LSTM (H=256), 45 steps, B=4096.
// R15: WEIGHT-STATIONARY groups. 16 groups x 16 WGs. Member m holds gate
// rows {g*256 + m*16 .. +15} of Whh0/Wih1/Whh1 in LDS (96KB, loaded once).
// Per step it computes its 64 gate rows for all 256 group batches, streaming
// only h-tiles (global, stored in MFMA A-frag layout -> one dwordx4/frag).
// h/pos exchanged via fenced global buffers + group-local generation barrier
// (16 arrivals; R13 empirically proved this barrier pattern completes at
// grid=256, 1 block/CU, across graph replays). gctx + c-state in registers.
// Fallback: if ws_size too small, runs the proven R10 kernel.
// mfma_f32_16x16x32_bf16: A row=lane&15(batch), k=(lane>>4)*8+j;
//   B col=lane&15(gate unit); C/D row=(lane>>4)*4+q, col=lane&15.

#define HN    256
#define DM    128
#define NSTEP 45
#define TPB   512

// ---- d_ws layout (bytes) ----
// weights tiles (chunk-major repack): 1,605,632
#define H0A_OFF  1605632
#define HBUF_B   2097152               // 4096*256*2
#define H0B_OFF  (H0A_OFF + HBUF_B)
#define H1A_OFF  (H0B_OFF + HBUF_B)
#define H1B_OFF  (H1A_OFF + HBUF_B)
#define POS_OFF  (H1B_OFF + HBUF_B)    // 4096*2*4 = 32768
#define BARS_OFF (POS_OFF + 32768)     // 16 groups * 64B
#define WS_NEED  (BARS_OFF + 1024)

typedef __attribute__((ext_vector_type(8))) short s8v;
typedef __attribute__((ext_vector_type(4))) float f32x4;

#define MFMA16(a,b,c) __builtin_amdgcn_mfma_f32_16x16x32_bf16((a),(b),(c),0,0,0)

__device__ __forceinline__ unsigned short f2bf(float f){
  union { float f; unsigned u; } x; x.f = f;
  unsigned r = x.u + 0x7fffu + ((x.u >> 16) & 1u);
  return (unsigned short)(r >> 16);
}
__device__ __forceinline__ float bf2f(unsigned short h){
  union { unsigned u; float f; } x; x.u = ((unsigned)h) << 16;
  return x.f;
}
__device__ __forceinline__ float sigm(float x){
  x = fminf(40.f, fmaxf(-40.f, x));
  return 1.f/(1.f + __expf(-x));
}
__device__ __forceinline__ float tanhx(float x){
  float xx = fminf(15.f, fmaxf(-15.f, x));
  float e = __expf(2.f*xx);
  return (e-1.f)/(e+1.f);
}

// h global tile layout (ushort): addr = blk*4096 + (u>>5)*512 + (b16 + ((u>>3)&3)*16)*8 + (u&7)
__device__ __forceinline__ void store_h(unsigned short* buf, int blk, int b16, int u, float v){
  buf[blk*4096 + (u>>5)*512 + (b16 + ((u>>3)&3)*16)*8 + (u&7)] = f2bf(v);
}
// A-frag read: lane gets batch=blk*16+(lane&15), k=kt*32+(lane>>4)*8+j
__device__ __forceinline__ s8v ld_af(const unsigned short* buf, int blk, int kt, int lane){
  return *(const s8v*)(buf + blk*4096 + kt*512 + lane*8);
}

// group-local generation barrier (16 members; gbar[0]=arrivals, gbar[1]=gen)
__device__ __forceinline__ void group_barrier(unsigned* gbar, unsigned gen){
  __syncthreads();
  if (threadIdx.x == 0){
    __threadfence();
    unsigned arrived = atomicAdd(gbar, 1u) + 1u;
    if (arrived == 16u*gen){
      __threadfence();
      atomicAdd(gbar+1, 1u);
    } else {
      unsigned spin = 0;
      while (atomicAdd(gbar+1, 0u) < gen && spin < (1u<<20)){
        __builtin_amdgcn_s_sleep(2); ++spin;
      }
    }
    __threadfence();
  }
  __syncthreads();
}

// ---- repack (chunk-major, same as R10): serves BOTH kernels ----
// d_ws (ushort): Whh0[262144] | Wih1[262144] | Whh1[262144] | Wp1[16384]
// big: tile r=(g*8+kt)*16+ut at mi*262144+r*512+lane*8 holds
//   W[g*256+ut*16+(lane&15)][kt*32+(lane>>4)*8+j]
// Wp1: tile r2=pt*8+kt at 786432+r2*512+lane*8, row pt*16+(lane&15).
__global__ void repack(const float* __restrict__ Whh0, const float* __restrict__ Wih1,
                       const float* __restrict__ Whh1, const float* __restrict__ Wp1,
                       unsigned short* __restrict__ dst){
  int gid  = blockIdx.x*256 + threadIdx.x;
  int lane = gid & 63;
  int tile = gid >> 6;
  const float* src; int row; size_t doff;
  int k0 = (lane>>4)*8;
  if (tile < 1536){
    int mi = tile / 512;
    int r  = tile % 512;
    int ut = r & 15;
    int kt = (r >> 4) & 7;
    int g  = r >> 7;
    src  = (mi==0) ? Whh0 : (mi==1) ? Wih1 : Whh1;
    row  = g*256 + ut*16 + (lane&15);
    k0  += kt*32;
    doff = (size_t)mi*262144 + (size_t)r*512 + lane*8;
  } else {
    int r2 = tile - 1536;
    int kt = r2 & 7, pt = r2 >> 3;
    src  = Wp1;
    row  = pt*16 + (lane&15);
    k0  += kt*32;
    doff = 786432 + (size_t)r2*512 + lane*8;
  }
  const float* s = src + (size_t)row*HN + k0;
  float4 a = *(const float4*)(s);
  float4 b = *(const float4*)(s+4);
  unsigned short* d = dst + doff;
  d[0]=f2bf(a.x); d[1]=f2bf(a.y); d[2]=f2bf(a.z); d[3]=f2bf(a.w);
  d[4]=f2bf(b.x); d[5]=f2bf(b.y); d[6]=f2bf(b.z); d[7]=f2bf(b.w);
}

// ===================== R15 weight-stationary kernel =====================
__global__ __launch_bounds__(TPB, 1)
void traj_ws(const float* __restrict__ enc,   // B x 128
             const float* __restrict__ pos0,  // B x 2
             const float* __restrict__ ctx,   // B x 128
             const float* __restrict__ Wh,    // 512 x 128
             const float* __restrict__ bh,
             const float* __restrict__ Wc,
             const float* __restrict__ bc,
             const float* __restrict__ Wih0,  // 1024 x 130
             const float* __restrict__ bih0,
             const float* __restrict__ bhh0,
             const float* __restrict__ bih1,
             const float* __restrict__ bhh1,
             const float* __restrict__ Wp2,
             const float* __restrict__ bp1,
             const float* __restrict__ bp2,
             const unsigned short* __restrict__ wsW,
             unsigned short* __restrict__ h0a, unsigned short* __restrict__ h0b,
             unsigned short* __restrict__ h1a, unsigned short* __restrict__ h1b,
             float* __restrict__ posb,
             unsigned* __restrict__ bars,
             float* __restrict__ out)
{
  __shared__ unsigned short sh_w[3*16384];  // 96KB member weight slices
  __shared__ float sh_scr[64*DM];           // 32KB init staging
  __shared__ float sh_red[4][16][2];

  const int tid  = threadIdx.x;
  const int lane = tid & 63;
  const int w    = tid >> 6;        // 8 waves
  const int col  = lane & 15;
  const int hi   = lane >> 4;
  const int G_   = blockIdx.x >> 4; // group
  const int m    = blockIdx.x & 15; // member
  const int gb0G = G_ * 256;        // group batch base
  const int ug   = m*16 + col;      // owned unit (0..255)
  unsigned* gbar = bars + G_*16;    // 64B line per group

  // ---- per-lane constants ----
  float wpr[4][2], b1r[4];
  #pragma unroll
  for (int g=0; g<4; g++){
    wpr[g][0] = Wih0[(size_t)(g*256+ug)*130 + 0];
    wpr[g][1] = Wih0[(size_t)(g*256+ug)*130 + 1];
    b1r[g]    = bih1[g*256+ug] + bhh1[g*256+ug];
  }
  const float bh0 = bh[ug], bh1v = bh[256+ug], bc0 = bc[ug], bc1v = bc[256+ug];
  const float bp1p = bp1[(w&3)*16 + col];
  const float w20  = Wp2[(w&3)*16 + col];
  const float w21  = Wp2[64 + (w&3)*16 + col];
  const float bp20 = bp2[0], bp21 = bp2[1];

  float c0r[2][4], c1r[2][4];
  unsigned gregp[2][4][2];

  // ---- INIT pass 1: enc -> h0/h1 tiles + c regs (4 quarters of 64 batches) ----
  #pragma nounroll
  for (int qi=0; qi<4; qi++){
    #pragma unroll 4
    for (int i=0;i<16;i++)
      sh_scr[tid + i*512] = enc[(size_t)(gb0G + qi*64)*DM + tid + i*512];
    __syncthreads();
    if ((w>>1) == qi){
      #pragma unroll
      for (int bb2=0; bb2<2; bb2++){
        #pragma unroll
        for (int q=0; q<4; q++){
          int lb = (w*2+bb2 - qi*4)*16 + hi*4 + q;
          const float* x  = &sh_scr[lb*DM];
          const float* r0 = Wh + (size_t)ug*DM;
          const float* r1 = Wh + (size_t)(256+ug)*DM;
          const float* r2 = Wc + (size_t)ug*DM;
          const float* r3 = Wc + (size_t)(256+ug)*DM;
          float a0=0.f,a1=0.f,a2=0.f,a3=0.f;
          #pragma nounroll
          for (int kk=0; kk<DM; kk++){
            float xv = x[kk];
            a0 += r0[kk]*xv; a1 += r1[kk]*xv; a2 += r2[kk]*xv; a3 += r3[kk]*xv;
          }
          int bg = gb0G + (w*2+bb2)*16 + hi*4 + q;
          store_h(h0a, bg>>4, bg&15, ug, a0 + bh0);
          store_h(h1a, bg>>4, bg&15, ug, a1 + bh1v);
          c0r[bb2][q] = a2 + bc0;
          c1r[bb2][q] = a3 + bc1v;
        }
      }
    }
    __syncthreads();
  }

  // ---- INIT pass 2: ctx -> gctx (packed bf16 regs) ----
  #pragma nounroll
  for (int qi=0; qi<4; qi++){
    #pragma unroll 4
    for (int i=0;i<16;i++)
      sh_scr[tid + i*512] = ctx[(size_t)(gb0G + qi*64)*DM + tid + i*512];
    __syncthreads();
    if ((w>>1) == qi){
      #pragma unroll
      for (int bb2=0; bb2<2; bb2++){
        #pragma unroll
        for (int g=0; g<4; g++){
          const float* rw = Wih0 + (size_t)(g*256+ug)*130 + 2;
          int lb0 = (w*2+bb2 - qi*4)*16 + hi*4;
          float a0=0.f,a1=0.f,a2=0.f,a3=0.f;
          #pragma nounroll
          for (int kk=0; kk<DM; kk++){
            float wv = rw[kk];
            a0 += wv*sh_scr[(lb0+0)*DM+kk];
            a1 += wv*sh_scr[(lb0+1)*DM+kk];
            a2 += wv*sh_scr[(lb0+2)*DM+kk];
            a3 += wv*sh_scr[(lb0+3)*DM+kk];
          }
          float b0 = bih0[g*256+ug] + bhh0[g*256+ug];
          gregp[bb2][g][0] = (unsigned)f2bf(a0+b0) | ((unsigned)f2bf(a1+b0) << 16);
          gregp[bb2][g][1] = (unsigned)f2bf(a2+b0) | ((unsigned)f2bf(a3+b0) << 16);
        }
      }
    }
    __syncthreads();
  }

  // ---- INIT: pos copy (own 16 batches) ----
  if (tid < 32) posb[(size_t)(gb0G + m*16)*2 + tid] = pos0[(size_t)(gb0G + m*16)*2 + tid];

  // ---- INIT: member weight slices -> LDS (96KB) ----
  // mat mt tile (g*8+kt) from global tile r=(g*8+kt)*16+m
  for (int it = tid; it < 6144; it += TPB){     // 3 mats * 32 tiles * 64 lane-slots
    int mt  = it >> 11;
    int rem = it & 2047;
    int tl  = rem >> 6;      // g*8+kt
    int ln  = rem & 63;
    const s8v* s = (const s8v*)(wsW + (size_t)mt*262144 + (size_t)(tl*16 + m)*512 + ln*8);
    *(s8v*)(sh_w + mt*16384 + tl*512 + ln*8) = *s;
  }

  group_barrier(gbar, 1u);   // init data visible group-wide

  const unsigned short* wp1t = wsW + 786432;

  // ================= 45-step rollout =================
  #pragma nounroll
  for (int t=0; t<NSTEP; t++){
    const unsigned short* h0rd = (t&1) ? h0b : h0a;
    unsigned short*       h0wr = (t&1) ? h0a : h0b;
    const unsigned short* h1rd = (t&1) ? h1b : h1a;
    unsigned short*       h1wr = (t&1) ? h1a : h1b;

    // ---------- Phase A: gates0 + cell0 ----------
    {
      s8v af[2][8];
      #pragma unroll
      for (int bb2=0; bb2<2; bb2++)
        #pragma unroll
        for (int kt=0; kt<8; kt++)
          af[bb2][kt] = ld_af(h0rd, G_*16 + w*2 + bb2, kt, lane);

      f32x4 acc[2][4];
      #pragma unroll
      for (int bb2=0; bb2<2; bb2++)
        #pragma unroll
        for (int j=0; j<2; j++)
          #pragma unroll
          for (int qq=0; qq<2; qq++){
            float2 pv = *(const float2*)(posb + 2*(gb0G + (w*2+bb2)*16 + hi*4 + 2*j+qq));
            #pragma unroll
            for (int g=0; g<4; g++){
              unsigned u = gregp[bb2][g][j];
              float gx = bf2f((unsigned short)(qq ? (u>>16) : (u & 0xffffu)));
              acc[bb2][g][2*j+qq] = gx + pv.x*wpr[g][0] + pv.y*wpr[g][1];
            }
          }

      #pragma unroll
      for (int kt=0; kt<8; kt++)
        #pragma unroll
        for (int g=0; g<4; g++){
          s8v wf = *(const s8v*)(sh_w + (g*8+kt)*512 + lane*8);
          acc[0][g] = MFMA16(af[0][kt], wf, acc[0][g]);
          acc[1][g] = MFMA16(af[1][kt], wf, acc[1][g]);
        }

      #pragma unroll
      for (int bb2=0; bb2<2; bb2++)
        #pragma unroll
        for (int q=0; q<4; q++){
          float iv = sigm(acc[bb2][0][q]), fv = sigm(acc[bb2][1][q]);
          float gv = tanhx(acc[bb2][2][q]), ov = sigm(acc[bb2][3][q]);
          float cv = fv*c0r[bb2][q] + iv*gv;
          c0r[bb2][q] = cv;
          store_h(h0wr, G_*16 + w*2 + bb2, hi*4+q, ug, ov*tanhx(cv));
        }
    }
    group_barrier(gbar, (unsigned)(2 + 3*t));

    // ---------- Phase B: gates1 + cell1 ----------
    {
      f32x4 acc[2][4];
      #pragma unroll
      for (int bb2=0; bb2<2; bb2++)
        #pragma unroll
        for (int g=0; g<4; g++)
          #pragma unroll
          for (int q=0; q<4; q++)
            acc[bb2][g][q] = b1r[g];

      {
        s8v af[2][8];
        #pragma unroll
        for (int bb2=0; bb2<2; bb2++)
          #pragma unroll
          for (int kt=0; kt<8; kt++)
            af[bb2][kt] = ld_af(h0wr, G_*16 + w*2 + bb2, kt, lane);
        #pragma unroll
        for (int kt=0; kt<8; kt++)
          #pragma unroll
          for (int g=0; g<4; g++){
            s8v wf = *(const s8v*)(sh_w + 16384 + (g*8+kt)*512 + lane*8);
            acc[0][g] = MFMA16(af[0][kt], wf, acc[0][g]);
            acc[1][g] = MFMA16(af[1][kt], wf, acc[1][g]);
          }
      }
      {
        s8v af[2][8];
        #pragma unroll
        for (int bb2=0; bb2<2; bb2++)
          #pragma unroll
          for (int kt=0; kt<8; kt++)
            af[bb2][kt] = ld_af(h1rd, G_*16 + w*2 + bb2, kt, lane);
        #pragma unroll
        for (int kt=0; kt<8; kt++)
          #pragma unroll
          for (int g=0; g<4; g++){
            s8v wf = *(const s8v*)(sh_w + 32768 + (g*8+kt)*512 + lane*8);
            acc[0][g] = MFMA16(af[0][kt], wf, acc[0][g]);
            acc[1][g] = MFMA16(af[1][kt], wf, acc[1][g]);
          }
      }

      #pragma unroll
      for (int bb2=0; bb2<2; bb2++)
        #pragma unroll
        for (int q=0; q<4; q++){
          float iv = sigm(acc[bb2][0][q]), fv = sigm(acc[bb2][1][q]);
          float gv = tanhx(acc[bb2][2][q]), ov = sigm(acc[bb2][3][q]);
          float cv = fv*c1r[bb2][q] + iv*gv;
          c1r[bb2][q] = cv;
          store_h(h1wr, G_*16 + w*2 + bb2, hi*4+q, ug, ov*tanhx(cv));
        }
    }
    group_barrier(gbar, (unsigned)(3 + 3*t));

    // ---------- Phase C: head + pos + out (own 16 batches) ----------
    if (w < 4){
      f32x4 hp = {bp1p, bp1p, bp1p, bp1p};
      #pragma unroll
      for (int kt=0; kt<8; kt++){
        s8v a  = ld_af(h1wr, G_*16 + m, kt, lane);
        s8v wf = *(const s8v*)(wp1t + (w*8+kt)*512 + lane*8);
        hp = MFMA16(a, wf, hp);
      }
      #pragma unroll
      for (int q=0; q<4; q++){
        float r  = fmaxf(hp[q], 0.f);
        float s0 = r*w20, s1 = r*w21;
        #pragma unroll
        for (int off=1; off<16; off<<=1){
          s0 += __shfl_xor(s0, off, 64);
          s1 += __shfl_xor(s1, off, 64);
        }
        if (col == 0){ sh_red[w][hi*4+q][0] = s0; sh_red[w][hi*4+q][1] = s1; }
      }
    }
    __syncthreads();
    if (tid < 32){
      int b = tid >> 1, d = tid & 1;
      int gb = gb0G + m*16 + b;
      float s = sh_red[0][b][d] + sh_red[1][b][d] + sh_red[2][b][d] + sh_red[3][b][d]
              + (d ? bp21 : bp20);
      float np = posb[(size_t)gb*2 + d] + s;
      posb[(size_t)gb*2 + d] = np;
      out[((size_t)gb*NSTEP + t)*2 + d] = np;
    }
    if (t < NSTEP-1) group_barrier(gbar, (unsigned)(4 + 3*t));
  }
}

// ===================== R10 fallback (proven 3.57ms) =====================
#define BBF    16
#define STAGEF(seq, bufi) do{ \
  const unsigned short* g_ = wsW + (size_t)(seq)*16384 + w*2048 + lane*8; \
  unsigned short* l_ = sh_stage + (bufi)*16384 + w*2048; \
  __builtin_amdgcn_global_load_lds((const __attribute__((address_space(1))) void*)(g_       ), (__attribute__((address_space(3))) void*)(l_       ), 16,0,0); \
  __builtin_amdgcn_global_load_lds((const __attribute__((address_space(1))) void*)(g_ +  512), (__attribute__((address_space(3))) void*)(l_ +  512), 16,0,0); \
  __builtin_amdgcn_global_load_lds((const __attribute__((address_space(1))) void*)(g_ + 1024), (__attribute__((address_space(3))) void*)(l_ + 1024), 16,0,0); \
  __builtin_amdgcn_global_load_lds((const __attribute__((address_space(1))) void*)(g_ + 1536), (__attribute__((address_space(3))) void*)(l_ + 1536), 16,0,0); \
}while(0)
#define CHUNKF(cl, MI, HS) do{ \
  const int c_  = (MI)*16 + (cl); \
  const int s2_ = (c_+2) % 48; \
  asm volatile("s_waitcnt vmcnt(4)" ::: "memory"); \
  __builtin_amdgcn_s_barrier(); \
  __builtin_amdgcn_sched_barrier(0); \
  STAGEF(s2_, (c_+2)%3); \
  const unsigned short* sb_ = sh_stage + (c_%3)*16384 + lane*8; \
  const int gI_ = (cl)>>2, kh_ = (cl)&3; \
  s8v aA_ = rdaf(HS, col, hi, 2*kh_+0); \
  s8v aB_ = rdaf(HS, col, hi, 2*kh_+1); \
  { s8v wf_ = *(const s8v*)(sb_ + (0*16 + (w*2+0))*512); acc[0][gI_] = MFMA16(aA_, wf_, acc[0][gI_]); } \
  { s8v wf_ = *(const s8v*)(sb_ + (0*16 + (w*2+1))*512); acc[1][gI_] = MFMA16(aA_, wf_, acc[1][gI_]); } \
  { s8v wf_ = *(const s8v*)(sb_ + (1*16 + (w*2+0))*512); acc[0][gI_] = MFMA16(aB_, wf_, acc[0][gI_]); } \
  { s8v wf_ = *(const s8v*)(sb_ + (1*16 + (w*2+1))*512); acc[1][gI_] = MFMA16(aB_, wf_, acc[1][gI_]); } \
}while(0)

__device__ __forceinline__ void wrh(unsigned short* lds, int b, int u, float v){
  lds[b*HN + (u ^ ((b&7)<<3))] = f2bf(v);
}
__device__ __forceinline__ s8v rdaf(const unsigned short* lds, int b, int hi, int kt){
  int blk = (kt*4 + hi) ^ (b & 7);
  return *(const s8v*)(lds + b*HN + blk*8);
}

__global__ __launch_bounds__(TPB, 1)
void traj_fb(const float* __restrict__ enc, const float* __restrict__ pos0,
             const float* __restrict__ ctx, const float* __restrict__ Wh,
             const float* __restrict__ bh,  const float* __restrict__ Wc,
             const float* __restrict__ bc,  const float* __restrict__ Wih0,
             const float* __restrict__ bih0,const float* __restrict__ bhh0,
             const float* __restrict__ bih1,const float* __restrict__ bhh1,
             const float* __restrict__ Wp2, const float* __restrict__ bp1,
             const float* __restrict__ bp2, const unsigned short* __restrict__ wsW,
             float* __restrict__ out)
{
  __shared__ unsigned short sh_stage[3*16384];
  __shared__ unsigned short sh_gx[BBF*1024];
  __shared__ unsigned short sh_h0u[BBF*HN];
  __shared__ unsigned short sh_h1u[BBF*HN];
  __shared__ float sh_pos[BBF][2];
  __shared__ float sh_red[4][BBF][2];

  const int tid  = threadIdx.x;
  const int gb0  = blockIdx.x * BBF;
  const int lane = tid & 63;
  const int w    = tid >> 6;
  const int col  = lane & 15;
  const int hi   = lane >> 4;
  float* sh_xf = (float*)sh_stage;

  { const float4* src = (const float4*)(enc + (size_t)gb0*DM);
    ((float4*)sh_xf)[tid] = src[tid]; }
  if (tid < BBF*2) ((float*)sh_pos)[tid] = pos0[(size_t)gb0*2 + tid];
  __syncthreads();
  {
    float* ctF = (float*)sh_gx;
    const int r = tid;
    float ah[BBF], ac[BBF];
    #pragma unroll
    for (int b=0;b<BBF;b++){ ah[b]=0.f; ac[b]=0.f; }
    const float4* whr = (const float4*)(Wh + (size_t)r*DM);
    const float4* wcr = (const float4*)(Wc + (size_t)r*DM);
    #pragma nounroll
    for (int kk=0; kk<DM/4; kk++){
      float4 w0 = whr[kk], w1 = wcr[kk];
      #pragma unroll
      for (int b=0;b<BBF;b++){
        float4 x = *(const float4*)&sh_xf[b*DM + kk*4];
        ah[b] += w0.x*x.x + w0.y*x.y + w0.z*x.z + w0.w*x.w;
        ac[b] += w1.x*x.x + w1.y*x.y + w1.z*x.z + w1.w*x.w;
      }
    }
    float bhv = bh[r], bcv = bc[r];
    if (r < HN){
      #pragma unroll
      for (int b=0;b<BBF;b++){ wrh(sh_h0u, b, r, ah[b]+bhv); ctF[(size_t)b*HN + r] = ac[b]+bcv; }
    } else {
      #pragma unroll
      for (int b=0;b<BBF;b++){ wrh(sh_h1u, b, r-HN, ah[b]+bhv); ctF[4096 + (size_t)b*HN + (r-HN)] = ac[b]+bcv; }
    }
  }
  __syncthreads();
  float c0r[2][4], c1r[2][4];
  {
    const float* ctF = (const float*)sh_gx;
    #pragma unroll
    for (int m=0;m<2;m++){
      int uu = (w*2+m)*16 + col;
      #pragma unroll
      for (int q=0;q<4;q++){
        int b = hi*4+q;
        c0r[m][q] = ctF[(size_t)b*HN + uu];
        c1r[m][q] = ctF[4096 + (size_t)b*HN + uu];
      }
    }
  }
  __syncthreads();
  { const float4* src = (const float4*)(ctx + (size_t)gb0*DM);
    ((float4*)sh_xf)[tid] = src[tid]; }
  __syncthreads();
  {
    float a0[BBF], a1[BBF];
    #pragma unroll
    for (int b=0;b<BBF;b++){ a0[b]=0.f; a1[b]=0.f; }
    const float2* wr0 = (const float2*)(Wih0 + (size_t)tid*130 + 2);
    const float2* wr1 = (const float2*)(Wih0 + (size_t)(tid+512)*130 + 2);
    #pragma nounroll
    for (int kk=0; kk<DM/2; kk++){
      float2 w0 = wr0[kk], w1 = wr1[kk];
      #pragma unroll
      for (int b=0;b<BBF;b++){
        float2 x = *(const float2*)&sh_xf[b*DM + kk*2];
        a0[b] += w0.x*x.x + w0.y*x.y;
        a1[b] += w1.x*x.x + w1.y*x.y;
      }
    }
    float cb0 = bih0[tid] + bhh0[tid];
    float cb1 = bih0[tid+512] + bhh0[tid+512];
    #pragma unroll
    for (int b=0;b<BBF;b++){
      sh_gx[(size_t)b*1024 + tid]       = f2bf(a0[b] + cb0);
      sh_gx[(size_t)b*1024 + tid + 512] = f2bf(a1[b] + cb1);
    }
  }
  float wpr[2][4][2]; float b1r[2][4];
  #pragma unroll
  for (int m=0;m<2;m++){
    int uu = (w*2+m)*16 + col;
    #pragma unroll
    for (int g=0;g<4;g++){
      int j = (g<<8) + uu;
      wpr[m][g][0] = Wih0[(size_t)j*130 + 0];
      wpr[m][g][1] = Wih0[(size_t)j*130 + 1];
      b1r[m][g]    = bih1[j] + bhh1[j];
    }
  }
  const float bp1p = bp1[(w&3)*16 + col];
  const float w20  = Wp2[(w&3)*16 + col];
  const float w21  = Wp2[64 + (w&3)*16 + col];
  const float bp20 = bp2[0], bp21 = bp2[1];
  const unsigned short* wTp = wsW + 786432 + lane*8;
  __syncthreads();
  STAGEF(0, 0);
  STAGEF(1, 1);
  #pragma nounroll
  for (int t=0; t<NSTEP; t++){
    f32x4 acc[2][4];
    #pragma unroll
    for (int m=0;m<2;m++){
      const int uu = (w*2+m)*16 + col;
      #pragma unroll
      for (int q=0;q<4;q++){
        float2 pp = *(const float2*)&sh_pos[hi*4+q][0];
        #pragma unroll
        for (int g=0;g<4;g++)
          acc[m][g][q] = bf2f(sh_gx[(size_t)(hi*4+q)*1024 + (g<<8) + uu])
                       + pp.x*wpr[m][g][0] + pp.y*wpr[m][g][1];
      }
    }
    #pragma unroll
    for (int cl=0; cl<16; cl++){ CHUNKF(cl, 0, sh_h0u); }
    __syncthreads();
    #pragma unroll
    for (int m=0;m<2;m++){
      int uu = (w*2+m)*16 + col;
      #pragma unroll
      for (int q=0;q<4;q++){
        float iv = sigm(acc[m][0][q]), fv = sigm(acc[m][1][q]);
        float gv = tanhx(acc[m][2][q]), ov = sigm(acc[m][3][q]);
        float cv = fv*c0r[m][q] + iv*gv;
        c0r[m][q] = cv;
        wrh(sh_h0u, hi*4+q, uu, ov*tanhx(cv));
      }
    }
    __syncthreads();
    #pragma unroll
    for (int m=0;m<2;m++)
      #pragma unroll
      for (int g=0;g<4;g++)
        #pragma unroll
        for (int q=0;q<4;q++)
          acc[m][g][q] = b1r[m][g];
    #pragma unroll
    for (int cl=0; cl<16; cl++){ CHUNKF(cl, 1, sh_h0u); }
    #pragma unroll
    for (int cl=0; cl<16; cl++){ CHUNKF(cl, 2, sh_h1u); }
    __syncthreads();
    #pragma unroll
    for (int m=0;m<2;m++){
      int uu = (w*2+m)*16 + col;
      #pragma unroll
      for (int q=0;q<4;q++){
        float iv = sigm(acc[m][0][q]), fv = sigm(acc[m][1][q]);
        float gv = tanhx(acc[m][2][q]), ov = sigm(acc[m][3][q]);
        float cv = fv*c1r[m][q] + iv*gv;
        c1r[m][q] = cv;
        wrh(sh_h1u, hi*4+q, uu, ov*tanhx(cv));
      }
    }
    __syncthreads();
    if (w < 4){
      f32x4 hp = {bp1p, bp1p, bp1p, bp1p};
      #pragma unroll
      for (int kt=0;kt<8;kt++){
        s8v a1n = rdaf(sh_h1u, col, hi, kt);
        s8v wfp = *(const s8v*)(wTp + (size_t)((w&3)*8+kt)*512);
        hp = MFMA16(a1n, wfp, hp);
      }
      #pragma unroll
      for (int q=0;q<4;q++){
        float r  = fmaxf(hp[q], 0.f);
        float s0 = r*w20, s1 = r*w21;
        #pragma unroll
        for (int off=1; off<16; off<<=1){
          s0 += __shfl_xor(s0, off, 64);
          s1 += __shfl_xor(s1, off, 64);
        }
        if (col == 0){ sh_red[w][hi*4+q][0] = s0; sh_red[w][hi*4+q][1] = s1; }
      }
    }
    __syncthreads();
    if (tid < BBF*2){
      int b = tid >> 1, d = tid & 1;
      float s = sh_red[0][b][d] + sh_red[1][b][d] + sh_red[2][b][d] + sh_red[3][b][d]
              + (d ? bp21 : bp20);
      float np = sh_pos[b][d] + s;
      sh_pos[b][d] = np;
      out[((size_t)(gb0+b)*NSTEP + t)*2 + d] = np;
    }
    __syncthreads();
  }
}

extern "C" void kernel_launch(void* const* d_in, const int* in_sizes, int n_in,
                              void* d_out, int out_size, void* d_ws, size_t ws_size,
                              hipStream_t stream) {
  const float* enc  = (const float*)d_in[0];
  const float* pos0 = (const float*)d_in[1];
  const float* ctx  = (const float*)d_in[2];
  const float* Wh   = (const float*)d_in[3];
  const float* bh   = (const float*)d_in[4];
  const float* Wc   = (const float*)d_in[5];
  const float* bc   = (const float*)d_in[6];
  const float* Wih0 = (const float*)d_in[7];
  const float* Whh0 = (const float*)d_in[8];
  const float* bih0 = (const float*)d_in[9];
  const float* bhh0 = (const float*)d_in[10];
  const float* Wih1 = (const float*)d_in[11];
  const float* Whh1 = (const float*)d_in[12];
  const float* bih1 = (const float*)d_in[13];
  const float* bhh1 = (const float*)d_in[14];
  const float* Wp1  = (const float*)d_in[15];
  const float* bp1  = (const float*)d_in[16];
  const float* Wp2  = (const float*)d_in[17];
  const float* bp2  = (const float*)d_in[18];
  float* out = (float*)d_out;
  unsigned short* wsW = (unsigned short*)d_ws;

  hipLaunchKernelGGL(repack, dim3(392), dim3(256), 0, stream,
                     Whh0, Wih1, Whh1, Wp1, wsW);

  if (ws_size >= (size_t)WS_NEED){
    unsigned short* h0a = (unsigned short*)((char*)d_ws + H0A_OFF);
    unsigned short* h0b = (unsigned short*)((char*)d_ws + H0B_OFF);
    unsigned short* h1a = (unsigned short*)((char*)d_ws + H1A_OFF);
    unsigned short* h1b = (unsigned short*)((char*)d_ws + H1B_OFF);
    float*    posb = (float*)((char*)d_ws + POS_OFF);
    unsigned* bars = (unsigned*)((char*)d_ws + BARS_OFF);
    hipMemsetAsync((void*)bars, 0, 1024, stream);
    hipLaunchKernelGGL(traj_ws, dim3(256), dim3(TPB), 0, stream,
                       enc, pos0, ctx, Wh, bh, Wc, bc, Wih0, bih0, bhh0,
                       bih1, bhh1, Wp2, bp1, bp2, wsW,
                       h0a, h0b, h1a, h1b, posb, bars, out);
  } else {
    hipLaunchKernelGGL(traj_fb, dim3(4096 / BBF), dim3(TPB), 0, stream,
                       enc, pos0, ctx, Wh, bh, Wc, bc, Wih0, bih0, bhh0,
                       bih1, bhh1, Wp2, bp1, bp2, wsW, out);
  }
}

// Round 16
// 4052.481 us; speedup vs baseline: 1.0175x; 1.0175x over previous
//
#include <hip/hip_runtime.h>

// TrajectoryDecoder: 2-layer LSTM (H=256), 45 steps, B=4096.
// R16: R10's proven chunk pipeline, deepened. BB=16, 256 WGs x 512 thr.
// 48 x 32KB chunks/step, FOUR buffers (128KB), stage 3-ahead, vmcnt(8).
// Phase boundaries are lgkmcnt-only barriers (no vmcnt drain) -> the
// global_load_lds pipeline never drains across phases or steps
// (48 % 4 == 0 keeps buffer indexing globally consistent).
// gctx in packed-bf16 registers (frees 32KB LDS for the 4th buffer).
// All loop indices compile-time (rule #20).
// mfma_f32_16x16x32_bf16: A row=lane&15(batch), k=(lane>>4)*8+j;
//   B col=lane&15(gate unit); C/D row=(lane>>4)*4+q, col=lane&15.

#define BB    16
#define TPB   512
#define HN    256
#define DM    128
#define NSTEP 45

typedef __attribute__((ext_vector_type(8))) short s8v;
typedef __attribute__((ext_vector_type(4))) float f32x4;

#define MFMA16(a,b,c) __builtin_amdgcn_mfma_f32_16x16x32_bf16((a),(b),(c),0,0,0)

__device__ __forceinline__ unsigned short f2bf(float f){
  union { float f; unsigned u; } x; x.f = f;
  unsigned r = x.u + 0x7fffu + ((x.u >> 16) & 1u);
  return (unsigned short)(r >> 16);
}
__device__ __forceinline__ float bf2f(unsigned short h){
  union { unsigned u; float f; } x; x.u = ((unsigned)h) << 16;
  return x.f;
}
__device__ __forceinline__ float sigm(float x){
  x = fminf(40.f, fmaxf(-40.f, x));
  return 1.f/(1.f + __expf(-x));
}
__device__ __forceinline__ float tanhx(float x){
  float xx = fminf(15.f, fmaxf(-15.f, x));
  float e = __expf(2.f*xx);
  return (e-1.f)/(e+1.f);
}

// h LDS: bf16 [16 rows][256], row b element u stored at u ^ ((b&7)<<3)
__device__ __forceinline__ void write_h(unsigned short* lds, int b, int u, float v){
  lds[b*HN + (u ^ ((b&7)<<3))] = f2bf(v);
}
__device__ __forceinline__ s8v read_afrag(const unsigned short* lds, int b, int hi, int kt){
  int blk = (kt*4 + hi) ^ (b & 7);
  return *(const s8v*)(lds + b*HN + blk*8);
}

// ---- repack (R10 layout): fp32 row-major -> bf16 tiles, CHUNK-MAJOR ----
// d_ws (ushort): Whh0[262144] | Wih1[262144] | Whh1[262144] | Wp1[16384]
// big: tile r=(g*8+kt)*16+ut at mi*262144+r*512+lane*8 holds
//   W[g*256+ut*16+(lane&15)][kt*32+(lane>>4)*8+j]
// chunk (g,kh)=32KB at (g*4+kh)*16384 contiguous (kt=2kh,2kh+1; all ut).
// Wp1: tile r2=pt*8+kt at 786432+r2*512+lane*8, row pt*16+(lane&15).
__global__ void repack(const float* __restrict__ Whh0, const float* __restrict__ Wih1,
                       const float* __restrict__ Whh1, const float* __restrict__ Wp1,
                       unsigned short* __restrict__ dst){
  int gid  = blockIdx.x*256 + threadIdx.x;
  int lane = gid & 63;
  int tile = gid >> 6;
  const float* src; int row; size_t doff;
  int k0 = (lane>>4)*8;
  if (tile < 1536){
    int mi = tile / 512;
    int r  = tile % 512;          // (g*8+kt)*16+ut
    int ut = r & 15;
    int kt = (r >> 4) & 7;
    int g  = r >> 7;
    src  = (mi==0) ? Whh0 : (mi==1) ? Wih1 : Whh1;
    row  = g*256 + ut*16 + (lane&15);
    k0  += kt*32;
    doff = (size_t)mi*262144 + (size_t)r*512 + lane*8;
  } else {
    int r2 = tile - 1536;         // pt*8+kt
    int kt = r2 & 7, pt = r2 >> 3;
    src  = Wp1;
    row  = pt*16 + (lane&15);
    k0  += kt*32;
    doff = 786432 + (size_t)r2*512 + lane*8;
  }
  const float* s = src + (size_t)row*HN + k0;
  float4 a = *(const float4*)(s);
  float4 b = *(const float4*)(s+4);
  unsigned short* d = dst + doff;
  d[0]=f2bf(a.x); d[1]=f2bf(a.y); d[2]=f2bf(a.z); d[3]=f2bf(a.w);
  d[4]=f2bf(b.x); d[5]=f2bf(b.y); d[6]=f2bf(b.z); d[7]=f2bf(b.w);
}

// stage one 32KB chunk into buffer bufi: wave w covers [w*2048,+2048) ushorts
#define STAGE(seq, bufi) do{ \
  const unsigned short* g_ = wsW + (size_t)(seq)*16384 + w*2048 + lane*8; \
  unsigned short* l_ = sh_stage + (size_t)(bufi)*16384 + w*2048; \
  __builtin_amdgcn_global_load_lds((const __attribute__((address_space(1))) void*)(g_       ), (__attribute__((address_space(3))) void*)(l_       ), 16,0,0); \
  __builtin_amdgcn_global_load_lds((const __attribute__((address_space(1))) void*)(g_ +  512), (__attribute__((address_space(3))) void*)(l_ +  512), 16,0,0); \
  __builtin_amdgcn_global_load_lds((const __attribute__((address_space(1))) void*)(g_ + 1024), (__attribute__((address_space(3))) void*)(l_ + 1024), 16,0,0); \
  __builtin_amdgcn_global_load_lds((const __attribute__((address_space(1))) void*)(g_ + 1536), (__attribute__((address_space(3))) void*)(l_ + 1536), 16,0,0); \
}while(0)

// one chunk: wait seq-c loads (12 out, keep 8), barrier, prefetch c+3, 4 MFMAs
#define CHUNK(cl, MI, HS) do{ \
  const int c_  = (MI)*16 + (cl); \
  const int s3_ = (c_+3) % 48; \
  asm volatile("s_waitcnt vmcnt(8)" ::: "memory"); \
  __builtin_amdgcn_s_barrier(); \
  __builtin_amdgcn_sched_barrier(0); \
  STAGE(s3_, (c_+3)&3); \
  const unsigned short* sb_ = sh_stage + (size_t)(c_&3)*16384 + lane*8; \
  const int gI_ = (cl)>>2, kh_ = (cl)&3; \
  s8v aA_ = read_afrag(HS, col, hi, 2*kh_+0); \
  s8v aB_ = read_afrag(HS, col, hi, 2*kh_+1); \
  { s8v wf_ = *(const s8v*)(sb_ + (0*16 + (w*2+0))*512); \
    acc[0][gI_] = MFMA16(aA_, wf_, acc[0][gI_]); } \
  { s8v wf_ = *(const s8v*)(sb_ + (0*16 + (w*2+1))*512); \
    acc[1][gI_] = MFMA16(aA_, wf_, acc[1][gI_]); } \
  { s8v wf_ = *(const s8v*)(sb_ + (1*16 + (w*2+0))*512); \
    acc[0][gI_] = MFMA16(aB_, wf_, acc[0][gI_]); } \
  { s8v wf_ = *(const s8v*)(sb_ + (1*16 + (w*2+1))*512); \
    acc[1][gI_] = MFMA16(aB_, wf_, acc[1][gI_]); } \
}while(0)

// phase barrier: publish LDS writes without draining vmcnt (keeps pipeline)
#define PHASE_BAR() do{ \
  asm volatile("s_waitcnt lgkmcnt(0)" ::: "memory"); \
  __builtin_amdgcn_s_barrier(); \
  __builtin_amdgcn_sched_barrier(0); \
}while(0)

__global__ __launch_bounds__(TPB, 1)
void traj_mfma(const float* __restrict__ enc,   // B x 128
               const float* __restrict__ pos0,  // B x 2
               const float* __restrict__ ctx,   // B x 128
               const float* __restrict__ Wh,    // 512 x 128
               const float* __restrict__ bh,
               const float* __restrict__ Wc,
               const float* __restrict__ bc,
               const float* __restrict__ Wih0,  // 1024 x 130
               const float* __restrict__ bih0,
               const float* __restrict__ bhh0,
               const float* __restrict__ bih1,
               const float* __restrict__ bhh1,
               const float* __restrict__ Wp2,   // 2 x 64
               const float* __restrict__ bp1,
               const float* __restrict__ bp2,
               const unsigned short* __restrict__ wsW,
               float* __restrict__ out)         // B x 45 x 2
{
  __shared__ unsigned short sh_stage[4*16384]; // 128KB 4-buffer rotation
  __shared__ unsigned short sh_h0u[BB*HN];     // 8KB bf16 swizzled
  __shared__ unsigned short sh_h1u[BB*HN];     // 8KB
  __shared__ float sh_pos[BB][2];
  __shared__ float sh_red[4][BB][2];

  const int tid  = threadIdx.x;
  const int gb0  = blockIdx.x * BB;
  const int lane = tid & 63;
  const int w    = tid >> 6;        // 8 waves
  const int col  = lane & 15;
  const int hi   = lane >> 4;

  float* sh_xf = (float*)sh_stage;                 // 8KB input overlay
  float* ctF   = (float*)(sh_stage + 16384);       // 32KB ct scratch (bytes 32-64K)
  unsigned short* gxs = sh_stage + 16384;          // 32KB gctx scratch (same region)

  // ---- stage encoder_feat + pos ----
  {
    const float4* src = (const float4*)(enc + (size_t)gb0*DM);
    ((float4*)sh_xf)[tid] = src[tid];
  }
  if (tid < BB*2) ((float*)sh_pos)[tid] = pos0[(size_t)gb0*2 + tid];
  __syncthreads();

  // ---- h/c init: thread r computes h_all/c_all row r (fp32) ----
  {
    const int r = tid;
    float ah[BB], ac[BB];
    #pragma unroll
    for (int b=0;b<BB;b++){ ah[b]=0.f; ac[b]=0.f; }
    const float4* whr = (const float4*)(Wh + (size_t)r*DM);
    const float4* wcr = (const float4*)(Wc + (size_t)r*DM);
    #pragma nounroll
    for (int kk=0; kk<DM/4; kk++){
      float4 w0 = whr[kk], w1 = wcr[kk];
      #pragma unroll
      for (int b=0;b<BB;b++){
        float4 x = *(const float4*)&sh_xf[b*DM + kk*4];
        ah[b] += w0.x*x.x + w0.y*x.y + w0.z*x.z + w0.w*x.w;
        ac[b] += w1.x*x.x + w1.y*x.y + w1.z*x.z + w1.w*x.w;
      }
    }
    float bhv = bh[r], bcv = bc[r];
    if (r < HN){
      #pragma unroll
      for (int b=0;b<BB;b++){
        write_h(sh_h0u, b, r, ah[b] + bhv);
        ctF[(size_t)b*HN + r] = ac[b] + bcv;
      }
    } else {
      #pragma unroll
      for (int b=0;b<BB;b++){
        write_h(sh_h1u, b, r-HN, ah[b] + bhv);
        ctF[4096 + (size_t)b*HN + (r-HN)] = ac[b] + bcv;
      }
    }
  }
  __syncthreads();

  // ---- hoist c-state to regs ----
  float c0r[2][4], c1r[2][4];
  {
    #pragma unroll
    for (int m=0;m<2;m++){
      int uu = (w*2+m)*16 + col;
      #pragma unroll
      for (int q=0;q<4;q++){
        int b = hi*4+q;
        c0r[m][q] = ctF[(size_t)b*HN + uu];
        c1r[m][q] = ctF[4096 + (size_t)b*HN + uu];
      }
    }
  }
  __syncthreads();   // ct region free

  // ---- stage context ----
  {
    const float4* src = (const float4*)(ctx + (size_t)gb0*DM);
    ((float4*)sh_xf)[tid] = src[tid];
  }
  __syncthreads();

  // ---- gates_ctx -> bf16 scratch; thread owns rows tid, tid+512 ----
  {
    float a0[BB], a1[BB];
    #pragma unroll
    for (int b=0;b<BB;b++){ a0[b]=0.f; a1[b]=0.f; }
    const float2* wr0 = (const float2*)(Wih0 + (size_t)tid*130 + 2);
    const float2* wr1 = (const float2*)(Wih0 + (size_t)(tid+512)*130 + 2);
    #pragma nounroll
    for (int kk=0; kk<DM/2; kk++){
      float2 w0 = wr0[kk], w1 = wr1[kk];
      #pragma unroll
      for (int b=0;b<BB;b++){
        float2 x = *(const float2*)&sh_xf[b*DM + kk*2];
        a0[b] += w0.x*x.x + w0.y*x.y;
        a1[b] += w1.x*x.x + w1.y*x.y;
      }
    }
    float cb0 = bih0[tid]     + bhh0[tid];
    float cb1 = bih0[tid+512] + bhh0[tid+512];
    #pragma unroll
    for (int b=0;b<BB;b++){
      gxs[(size_t)b*1024 + tid]       = f2bf(a0[b] + cb0);
      gxs[(size_t)b*1024 + tid + 512] = f2bf(a1[b] + cb1);
    }
  }
  __syncthreads();

  // ---- hoist gctx to PACKED bf16 regs: gregp[m][g][j] (j = batch-pair) ----
  unsigned gregp[2][4][2];
  {
    #pragma unroll
    for (int m=0;m<2;m++){
      int uu = (w*2+m)*16 + col;
      #pragma unroll
      for (int g=0;g<4;g++)
        #pragma unroll
        for (int j=0;j<2;j++){
          unsigned lo = gxs[(size_t)(hi*4+2*j  )*1024 + (g<<8) + uu];
          unsigned hv = gxs[(size_t)(hi*4+2*j+1)*1024 + (g<<8) + uu];
          gregp[m][g][j] = lo | (hv << 16);
        }
    }
  }

  // ---- per-lane constants ----
  float wpr[2][4][2]; float b1r[2][4];
  #pragma unroll
  for (int m=0;m<2;m++){
    int uu = (w*2+m)*16 + col;
    #pragma unroll
    for (int g=0;g<4;g++){
      int j = (g<<8) + uu;
      wpr[m][g][0] = Wih0[(size_t)j*130 + 0];
      wpr[m][g][1] = Wih0[(size_t)j*130 + 1];
      b1r[m][g]    = bih1[j] + bhh1[j];
    }
  }
  const float bp1p = bp1[(w&3)*16 + col];
  const float w20  = Wp2[(w&3)*16 + col];
  const float w21  = Wp2[64 + (w&3)*16 + col];
  const float bp20 = bp2[0], bp21 = bp2[1];
  const unsigned short* wTp = wsW + 786432 + lane*8;   // Wp1 tiles
  __syncthreads();   // gxs scratch free -> all 4 stage buffers available

  // ---- prologue: stage chunks 0,1,2 (depth 3) ----
  STAGE(0, 0);
  STAGE(1, 1);
  STAGE(2, 2);

  // ================= 45-step rollout =================
  #pragma nounroll
  for (int t=0; t<NSTEP; t++){
    // ---- layer0 acc init: gctx(packed regs) + pos ----
    f32x4 acc[2][4];
    {
      float p0q[4], p1q[4];
      #pragma unroll
      for (int q=0;q<4;q++){
        float2 pp = *(const float2*)&sh_pos[hi*4+q][0];
        p0q[q]=pp.x; p1q[q]=pp.y;
      }
      #pragma unroll
      for (int m=0;m<2;m++)
        #pragma unroll
        for (int g=0;g<4;g++)
          #pragma unroll
          for (int j=0;j<2;j++){
            unsigned u = gregp[m][g][j];
            acc[m][g][2*j]   = bf2f((unsigned short)(u & 0xffffu))
                             + p0q[2*j]  *wpr[m][g][0] + p1q[2*j]  *wpr[m][g][1];
            acc[m][g][2*j+1] = bf2f((unsigned short)(u >> 16))
                             + p0q[2*j+1]*wpr[m][g][0] + p1q[2*j+1]*wpr[m][g][1];
          }
    }

    // ---- Whh0 chunks 0..15 (A = h0 old) ----
    #pragma unroll
    for (int cl=0; cl<16; cl++){ CHUNK(cl, 0, sh_h0u); }
    PHASE_BAR();   // all h0-old ds_reads complete

    // ---- cell0 ----
    #pragma unroll
    for (int m=0;m<2;m++){
      int uu = (w*2+m)*16 + col;
      #pragma unroll
      for (int q=0;q<4;q++){
        float iv = sigm(acc[m][0][q]), fv = sigm(acc[m][1][q]);
        float gv = tanhx(acc[m][2][q]), ov = sigm(acc[m][3][q]);
        float cv = fv*c0r[m][q] + iv*gv;
        c0r[m][q] = cv;
        write_h(sh_h0u, hi*4+q, uu, ov*tanhx(cv));
      }
    }
    PHASE_BAR();   // new h0 published

    // ---- layer1 acc init ----
    #pragma unroll
    for (int m=0;m<2;m++)
      #pragma unroll
      for (int g=0;g<4;g++)
        #pragma unroll
        for (int q=0;q<4;q++)
          acc[m][g][q] = b1r[m][g];

    // ---- Wih1 chunks 16..31 (A = h0 new), Whh1 chunks 32..47 (A = h1 old) ----
    #pragma unroll
    for (int cl=0; cl<16; cl++){ CHUNK(cl, 1, sh_h0u); }
    #pragma unroll
    for (int cl=0; cl<16; cl++){ CHUNK(cl, 2, sh_h1u); }
    PHASE_BAR();   // all h1-old ds_reads complete

    // ---- cell1 ----
    #pragma unroll
    for (int m=0;m<2;m++){
      int uu = (w*2+m)*16 + col;
      #pragma unroll
      for (int q=0;q<4;q++){
        float iv = sigm(acc[m][0][q]), fv = sigm(acc[m][1][q]);
        float gv = tanhx(acc[m][2][q]), ov = sigm(acc[m][3][q]);
        float cv = fv*c1r[m][q] + iv*gv;
        c1r[m][q] = cv;
        write_h(sh_h1u, hi*4+q, uu, ov*tanhx(cv));
      }
    }
    PHASE_BAR();   // new h1 published

    // ---- head (waves 0..3; p-unit = (w&3)*16+col), Wp1 direct from L2 ----
    if (w < 4){
      f32x4 hp = {bp1p, bp1p, bp1p, bp1p};
      #pragma unroll
      for (int kt=0;kt<8;kt++){
        s8v a1n = read_afrag(sh_h1u, col, hi, kt);
        s8v wfp = *(const s8v*)(wTp + (size_t)((w&3)*8+kt)*512);
        hp = MFMA16(a1n, wfp, hp);
      }
      #pragma unroll
      for (int q=0;q<4;q++){
        float r  = fmaxf(hp[q], 0.f);
        float s0 = r*w20, s1 = r*w21;
        #pragma unroll
        for (int off=1; off<16; off<<=1){
          s0 += __shfl_xor(s0, off, 64);
          s1 += __shfl_xor(s1, off, 64);
        }
        if (col == 0){ sh_red[w][hi*4+q][0] = s0; sh_red[w][hi*4+q][1] = s1; }
      }
    }
    PHASE_BAR();   // sh_red complete

    // ---- combine, update pos, write out ----
    if (tid < BB*2){
      int b = tid >> 1, d = tid & 1;
      float s = sh_red[0][b][d] + sh_red[1][b][d] + sh_red[2][b][d] + sh_red[3][b][d]
              + (d ? bp21 : bp20);
      float np = sh_pos[b][d] + s;
      sh_pos[b][d] = np;
      out[((size_t)(gb0+b)*NSTEP + t)*2 + d] = np;
    }
    PHASE_BAR();   // pos stable for next step
  }

  // drain any wrapped prefetches before endpgm
  asm volatile("s_waitcnt vmcnt(0)" ::: "memory");
}

extern "C" void kernel_launch(void* const* d_in, const int* in_sizes, int n_in,
                              void* d_out, int out_size, void* d_ws, size_t ws_size,
                              hipStream_t stream) {
  const float* enc  = (const float*)d_in[0];
  const float* pos0 = (const float*)d_in[1];
  const float* ctx  = (const float*)d_in[2];
  const float* Wh   = (const float*)d_in[3];
  const float* bh   = (const float*)d_in[4];
  const float* Wc   = (const float*)d_in[5];
  const float* bc   = (const float*)d_in[6];
  const float* Wih0 = (const float*)d_in[7];
  const float* Whh0 = (const float*)d_in[8];
  const float* bih0 = (const float*)d_in[9];
  const float* bhh0 = (const float*)d_in[10];
  const float* Wih1 = (const float*)d_in[11];
  const float* Whh1 = (const float*)d_in[12];
  const float* bih1 = (const float*)d_in[13];
  const float* bhh1 = (const float*)d_in[14];
  const float* Wp1  = (const float*)d_in[15];
  const float* bp1  = (const float*)d_in[16];
  const float* Wp2  = (const float*)d_in[17];
  const float* bp2  = (const float*)d_in[18];
  float* out = (float*)d_out;
  unsigned short* wsW = (unsigned short*)d_ws;

  hipLaunchKernelGGL(repack, dim3(392), dim3(256), 0, stream,
                     Whh0, Wih1, Whh1, Wp1, wsW);

  const int B = 4096;
  hipLaunchKernelGGL(traj_mfma, dim3(B / BB), dim3(TPB), 0, stream,
                     enc, pos0, ctx, Wh, bh, Wc, bc, Wih0, bih0, bhh0,
                     bih1, bhh1, Wp2, bp1, bp2, wsW, out);
}

// Round 17
// 3132.778 us; speedup vs baseline: 1.3161x; 1.2936x over previous
//
#include <hip/hip_runtime.h>

// TrajectoryDecoder: 2-layer LSTM (H=256), 45 steps, B=4096.
// R17: MULTI-KERNEL GEMM TILING. 3 kernels per step (45x3 dispatches,
// graph-captured): k1 layer0, k2 layer1, k3 head. Grid k1/k2 = 32
// batch-tiles x 8 unit-slices (256 WGs x 256 thr): each WG computes
// M=128 batches x N=128 gate rows, so each weight line is reused 128x
// -> weight demand 48MB/step (vs 384MB/step for the persistent design).
// Cross-WG h/pos coherence comes FREE from kernel boundaries (no
// barriers, fences, or atomics anywhere). State in d_ws: h0/h1 double
// buffers (A-frag tile layout), gctx bf16, c0/c1 fp32, pos fp32.
// Falls back to the proven R16 persistent kernel if ws_size too small.
// mfma_f32_16x16x32_bf16: A row=lane&15(batch), k=(lane>>4)*8+j;
//   B col=lane&15(gate unit); C/D row=(lane>>4)*4+q, col=lane&15.

#define HN    256
#define DM    128
#define NSTEP 45

// ---- d_ws layout (bytes) ----
#define WSW_B    1605632ULL                 // repacked weights (ushort[802816])
#define H0A_OFF  1605632ULL
#define HBUF_B   2097152ULL                 // 4096*256*2 bytes
#define H0B_OFF  (H0A_OFF + HBUF_B)
#define H1A_OFF  (H0B_OFF + HBUF_B)
#define H1B_OFF  (H1A_OFF + HBUF_B)
#define GX_OFF   (H1B_OFF + HBUF_B)         // gctx bf16 [256 blk][1024 row][16 b]
#define GX_B     8388608ULL
#define C0_OFF   (GX_OFF + GX_B)            // c0 fp32 [256 blk][256 u][16 b]
#define CB_B     4194304ULL
#define C1_OFF   (C0_OFF + CB_B)
#define POS_OFF  (C1_OFF + CB_B)            // pos fp32 [4096][2]
#define WS_NEED  (POS_OFF + 32768ULL)

typedef __attribute__((ext_vector_type(8))) short s8v;
typedef __attribute__((ext_vector_type(4))) float f32x4;

#define MFMA16(a,b,c) __builtin_amdgcn_mfma_f32_16x16x32_bf16((a),(b),(c),0,0,0)

__device__ __forceinline__ unsigned short f2bf(float f){
  union { float f; unsigned u; } x; x.f = f;
  unsigned r = x.u + 0x7fffu + ((x.u >> 16) & 1u);
  return (unsigned short)(r >> 16);
}
__device__ __forceinline__ float bf2f(unsigned short h){
  union { unsigned u; float f; } x; x.u = ((unsigned)h) << 16;
  return x.f;
}
__device__ __forceinline__ float sigm(float x){
  x = fminf(40.f, fmaxf(-40.f, x));
  return 1.f/(1.f + __expf(-x));
}
__device__ __forceinline__ float tanhx(float x){
  float xx = fminf(15.f, fmaxf(-15.f, x));
  float e = __expf(2.f*xx);
  return (e-1.f)/(e+1.f);
}

// h tile layout (verified in R15): elem (blk, b, u) at
//   blk*4096 + (u>>5)*512 + ((b&15) + ((u>>3)&3)*16)*8 + (u&7)   [ushorts]
__device__ __forceinline__ void store_h(unsigned short* buf, int blk, int b, int u, float v){
  buf[(size_t)blk*4096 + (u>>5)*512 + ((b&15) + ((u>>3)&3)*16)*8 + (u&7)] = f2bf(v);
}
__device__ __forceinline__ s8v ld_af(const unsigned short* buf, int blk, int kt, int lane){
  return *(const s8v*)(buf + (size_t)blk*4096 + kt*512 + lane*8);
}

// ---- repack (unchanged, verified): fp32 -> bf16 B-frag tiles ----
// d_ws (ushort): Whh0[262144] | Wih1[262144] | Whh1[262144] | Wp1[16384]
// big: tile r=(g*8+kt)*16+ut at mi*262144+r*512+lane*8 holds
//   W[g*256+ut*16+(lane&15)][kt*32+(lane>>4)*8+j]
// Wp1: tile r2=pt*8+kt at 786432+r2*512+lane*8, row pt*16+(lane&15).
__global__ void repack(const float* __restrict__ Whh0, const float* __restrict__ Wih1,
                       const float* __restrict__ Whh1, const float* __restrict__ Wp1,
                       unsigned short* __restrict__ dst){
  int gid  = blockIdx.x*256 + threadIdx.x;
  int lane = gid & 63;
  int tile = gid >> 6;
  const float* src; int row; size_t doff;
  int k0 = (lane>>4)*8;
  if (tile < 1536){
    int mi = tile / 512;
    int r  = tile % 512;
    int ut = r & 15;
    int kt = (r >> 4) & 7;
    int g  = r >> 7;
    src  = (mi==0) ? Whh0 : (mi==1) ? Wih1 : Whh1;
    row  = g*256 + ut*16 + (lane&15);
    k0  += kt*32;
    doff = (size_t)mi*262144 + (size_t)r*512 + lane*8;
  } else {
    int r2 = tile - 1536;
    int kt = r2 & 7, pt = r2 >> 3;
    src  = Wp1;
    row  = pt*16 + (lane&15);
    k0  += kt*32;
    doff = 786432 + (size_t)r2*512 + lane*8;
  }
  const float* s = src + (size_t)row*HN + k0;
  float4 a = *(const float4*)(s);
  float4 b = *(const float4*)(s+4);
  unsigned short* d = dst + doff;
  d[0]=f2bf(a.x); d[1]=f2bf(a.y); d[2]=f2bf(a.z); d[3]=f2bf(a.w);
  d[4]=f2bf(b.x); d[5]=f2bf(b.y); d[6]=f2bf(b.z); d[7]=f2bf(b.w);
}

// ===================== init: h/c/gctx/pos state =====================
__global__ __launch_bounds__(512, 1)
void k_init(const float* __restrict__ enc, const float* __restrict__ pos0,
            const float* __restrict__ ctx, const float* __restrict__ Wh,
            const float* __restrict__ bh,  const float* __restrict__ Wc,
            const float* __restrict__ bc,  const float* __restrict__ Wih0,
            const float* __restrict__ bih0,const float* __restrict__ bhh0,
            unsigned short* __restrict__ h0a, unsigned short* __restrict__ h1a,
            unsigned short* __restrict__ gxg,
            float* __restrict__ c0g, float* __restrict__ c1g,
            float* __restrict__ posg)
{
  __shared__ float sh_x[16*DM];   // 8KB
  const int tid = threadIdx.x;
  const int blk = blockIdx.x;     // 16 batches
  const int gb0 = blk*16;

  // stage enc
  {
    const float4* src = (const float4*)(enc + (size_t)gb0*DM);
    ((float4*)sh_x)[tid] = src[tid];
  }
  if (tid < 32) posg[(size_t)gb0*2 + tid] = pos0[(size_t)gb0*2 + tid];
  __syncthreads();

  // h/c rows: thread r -> row r of h_all/c_all (r<256: layer0; else layer1)
  {
    const int r = tid;
    float ah[16], ac[16];
    #pragma unroll
    for (int b=0;b<16;b++){ ah[b]=0.f; ac[b]=0.f; }
    const float4* whr = (const float4*)(Wh + (size_t)r*DM);
    const float4* wcr = (const float4*)(Wc + (size_t)r*DM);
    #pragma nounroll
    for (int kk=0; kk<DM/4; kk++){
      float4 w0 = whr[kk], w1 = wcr[kk];
      #pragma unroll
      for (int b=0;b<16;b++){
        float4 x = *(const float4*)&sh_x[b*DM + kk*4];
        ah[b] += w0.x*x.x + w0.y*x.y + w0.z*x.z + w0.w*x.w;
        ac[b] += w1.x*x.x + w1.y*x.y + w1.z*x.z + w1.w*x.w;
      }
    }
    float bhv = bh[r], bcv = bc[r];
    if (r < HN){
      #pragma unroll
      for (int b=0;b<16;b++){
        store_h(h0a, blk, b, r, ah[b] + bhv);
        c0g[(size_t)blk*4096 + r*16 + b] = ac[b] + bcv;
      }
    } else {
      #pragma unroll
      for (int b=0;b<16;b++){
        store_h(h1a, blk, b, r-HN, ah[b] + bhv);
        c1g[(size_t)blk*4096 + (r-HN)*16 + b] = ac[b] + bcv;
      }
    }
  }
  __syncthreads();

  // stage ctx
  {
    const float4* src = (const float4*)(ctx + (size_t)gb0*DM);
    ((float4*)sh_x)[tid] = src[tid];
  }
  __syncthreads();

  // gctx rows tid and tid+512 (incl bias0)
  {
    float a0[16], a1[16];
    #pragma unroll
    for (int b=0;b<16;b++){ a0[b]=0.f; a1[b]=0.f; }
    const float2* wr0 = (const float2*)(Wih0 + (size_t)tid*130 + 2);
    const float2* wr1 = (const float2*)(Wih0 + (size_t)(tid+512)*130 + 2);
    #pragma nounroll
    for (int kk=0; kk<DM/2; kk++){
      float2 w0 = wr0[kk], w1 = wr1[kk];
      #pragma unroll
      for (int b=0;b<16;b++){
        float2 x = *(const float2*)&sh_x[b*DM + kk*2];
        a0[b] += w0.x*x.x + w0.y*x.y;
        a1[b] += w1.x*x.x + w1.y*x.y;
      }
    }
    float cb0 = bih0[tid]     + bhh0[tid];
    float cb1 = bih0[tid+512] + bhh0[tid+512];
    #pragma unroll
    for (int b=0;b<16;b++){
      gxg[(size_t)blk*16384 + (size_t)tid*16 + b]       = f2bf(a0[b] + cb0);
      gxg[(size_t)blk*16384 + (size_t)(tid+512)*16 + b] = f2bf(a1[b] + cb1);
    }
  }
}

// ===================== k1: layer0 gates + cell =====================
// grid: bt(0..31) * 8 + sl(0..7); TPB 256 (4 waves). M=128, N=128, K=256.
__global__ __launch_bounds__(256, 2)
void k_layer0(const unsigned short* __restrict__ wsW,
              const unsigned short* __restrict__ gxg,
              const unsigned short* __restrict__ h0rd,
              unsigned short* __restrict__ h0wr,
              float* __restrict__ c0g,
              const float* __restrict__ posg,
              const float* __restrict__ Wih0)
{
  const int tid  = threadIdx.x;
  const int lane = tid & 63;
  const int w    = tid >> 6;       // 0..3
  const int col  = lane & 15;
  const int hi   = lane >> 4;
  const int bt   = blockIdx.x >> 3;
  const int sl   = blockIdx.x & 7;

  // per-lane row constants: n = g*2 + h2; row = g*256 + sl*32 + h2*16 + col
  float wpr[8][2];
  #pragma unroll
  for (int n=0;n<8;n++){
    int row = (n>>1)*256 + sl*32 + (n&1)*16 + col;
    wpr[n][0] = Wih0[(size_t)row*130 + 0];
    wpr[n][1] = Wih0[(size_t)row*130 + 1];
  }

  const int blk0 = bt*8 + w*2;
  const int blk1 = blk0 + 1;

  f32x4 acc[2][8];
  // acc init: gctx + pos @ Wpos
  #pragma unroll
  for (int m2=0;m2<2;m2++){
    const int blk = m2 ? blk1 : blk0;
    float p0[4], p1[4];
    #pragma unroll
    for (int q=0;q<4;q++){
      float2 pv = *(const float2*)(posg + (size_t)(blk*16 + hi*4 + q)*2);
      p0[q]=pv.x; p1[q]=pv.y;
    }
    #pragma unroll
    for (int n=0;n<8;n++){
      int row = (n>>1)*256 + sl*32 + (n&1)*16 + col;
      const unsigned short* gp = gxg + (size_t)blk*16384 + (size_t)row*16 + hi*4;
      #pragma unroll
      for (int q=0;q<4;q++)
        acc[m2][n][q] = bf2f(gp[q]) + p0[q]*wpr[n][0] + p1[q]*wpr[n][1];
    }
  }

  // MFMA main: B-frag tile r=(g*8+kt)*16 + (sl*2 + h2)
  #pragma unroll
  for (int kt=0;kt<8;kt++){
    s8v a0 = ld_af(h0rd, blk0, kt, lane);
    s8v a1 = ld_af(h0rd, blk1, kt, lane);
    #pragma unroll
    for (int n=0;n<8;n++){
      const int r = ((n>>1)*8 + kt)*16 + sl*2 + (n&1);
      s8v bf = *(const s8v*)(wsW + (size_t)r*512 + lane*8);
      acc[0][n] = MFMA16(a0, bf, acc[0][n]);
      acc[1][n] = MFMA16(a1, bf, acc[1][n]);
    }
  }

  // cell0: lane has i,f,g,o for unit u = sl*32 + h2*16 + col
  #pragma unroll
  for (int m2=0;m2<2;m2++){
    const int blk = m2 ? blk1 : blk0;
    #pragma unroll
    for (int h2=0;h2<2;h2++){
      const int u = sl*32 + h2*16 + col;
      float* cp = c0g + (size_t)blk*4096 + u*16 + hi*4;
      float4 cold = *(const float4*)cp;
      float4 cnew;
      #pragma unroll
      for (int q=0;q<4;q++){
        float iv = sigm(acc[m2][0+h2][q]);
        float fv = sigm(acc[m2][2+h2][q]);
        float gv = tanhx(acc[m2][4+h2][q]);
        float ov = sigm(acc[m2][6+h2][q]);
        float cv = fv*((&cold.x)[q]) + iv*gv;
        (&cnew.x)[q] = cv;
        store_h(h0wr, blk, hi*4+q, u, ov*tanhx(cv));
      }
      *(float4*)cp = cnew;
    }
  }
}

// ===================== k2: layer1 gates + cell =====================
__global__ __launch_bounds__(256, 2)
void k_layer1(const unsigned short* __restrict__ wsW,
              const unsigned short* __restrict__ h0n,   // h0 new (A for Wih1)
              const unsigned short* __restrict__ h1rd,  // h1 old (A for Whh1)
              unsigned short* __restrict__ h1wr,
              float* __restrict__ c1g,
              const float* __restrict__ bih1,
              const float* __restrict__ bhh1)
{
  const int tid  = threadIdx.x;
  const int lane = tid & 63;
  const int w    = tid >> 6;
  const int col  = lane & 15;
  const int hi   = lane >> 4;
  const int bt   = blockIdx.x >> 3;
  const int sl   = blockIdx.x & 7;

  const int blk0 = bt*8 + w*2;
  const int blk1 = blk0 + 1;

  f32x4 acc[2][8];
  #pragma unroll
  for (int n=0;n<8;n++){
    int row = (n>>1)*256 + sl*32 + (n&1)*16 + col;
    float bv = bih1[row] + bhh1[row];
    #pragma unroll
    for (int q=0;q<4;q++){ acc[0][n][q] = bv; acc[1][n][q] = bv; }
  }

  // phase A: Wih1 @ h0new
  #pragma unroll
  for (int kt=0;kt<8;kt++){
    s8v a0 = ld_af(h0n, blk0, kt, lane);
    s8v a1 = ld_af(h0n, blk1, kt, lane);
    #pragma unroll
    for (int n=0;n<8;n++){
      const int r = ((n>>1)*8 + kt)*16 + sl*2 + (n&1);
      s8v bf = *(const s8v*)(wsW + 262144 + (size_t)r*512 + lane*8);
      acc[0][n] = MFMA16(a0, bf, acc[0][n]);
      acc[1][n] = MFMA16(a1, bf, acc[1][n]);
    }
  }
  // phase B: Whh1 @ h1old
  #pragma unroll
  for (int kt=0;kt<8;kt++){
    s8v a0 = ld_af(h1rd, blk0, kt, lane);
    s8v a1 = ld_af(h1rd, blk1, kt, lane);
    #pragma unroll
    for (int n=0;n<8;n++){
      const int r = ((n>>1)*8 + kt)*16 + sl*2 + (n&1);
      s8v bf = *(const s8v*)(wsW + 524288 + (size_t)r*512 + lane*8);
      acc[0][n] = MFMA16(a0, bf, acc[0][n]);
      acc[1][n] = MFMA16(a1, bf, acc[1][n]);
    }
  }

  // cell1
  #pragma unroll
  for (int m2=0;m2<2;m2++){
    const int blk = m2 ? blk1 : blk0;
    #pragma unroll
    for (int h2=0;h2<2;h2++){
      const int u = sl*32 + h2*16 + col;
      float* cp = c1g + (size_t)blk*4096 + u*16 + hi*4;
      float4 cold = *(const float4*)cp;
      float4 cnew;
      #pragma unroll
      for (int q=0;q<4;q++){
        float iv = sigm(acc[m2][0+h2][q]);
        float fv = sigm(acc[m2][2+h2][q]);
        float gv = tanhx(acc[m2][4+h2][q]);
        float ov = sigm(acc[m2][6+h2][q]);
        float cv = fv*((&cold.x)[q]) + iv*gv;
        (&cnew.x)[q] = cv;
        store_h(h1wr, blk, hi*4+q, u, ov*tanhx(cv));
      }
      *(float4*)cp = cnew;
    }
  }
}

// ===================== k3: head + pos + out =====================
// grid: 32 (batch-tiles of 128); TPB 256 (4 waves, 2 m-tiles each).
__global__ __launch_bounds__(256, 2)
void k_head(const unsigned short* __restrict__ wsW,
            const unsigned short* __restrict__ h1n,
            float* __restrict__ posg,
            const float* __restrict__ bp1,
            const float* __restrict__ Wp2,
            const float* __restrict__ bp2,
            float* __restrict__ out, int t)
{
  const int tid  = threadIdx.x;
  const int lane = tid & 63;
  const int w    = tid >> 6;
  const int col  = lane & 15;
  const int hi   = lane >> 4;
  const int bt   = blockIdx.x;

  float bp[4], w2a[4], w2b[4];
  #pragma unroll
  for (int n=0;n<4;n++){
    bp[n]  = bp1[n*16 + col];
    w2a[n] = Wp2[n*16 + col];
    w2b[n] = Wp2[64 + n*16 + col];
  }
  const float bp20 = bp2[0], bp21 = bp2[1];

  #pragma unroll
  for (int m2=0;m2<2;m2++){
    const int blk = bt*8 + w*2 + m2;
    f32x4 acc[4];
    #pragma unroll
    for (int n=0;n<4;n++)
      #pragma unroll
      for (int q=0;q<4;q++) acc[n][q] = bp[n];
    #pragma unroll
    for (int kt=0;kt<8;kt++){
      s8v a = ld_af(h1n, blk, kt, lane);
      #pragma unroll
      for (int n=0;n<4;n++){
        s8v bf = *(const s8v*)(wsW + 786432 + (size_t)(n*8+kt)*512 + lane*8);
        acc[n] = MFMA16(a, bf, acc[n]);
      }
    }
    #pragma unroll
    for (int q=0;q<4;q++){
      float s0 = 0.f, s1 = 0.f;
      #pragma unroll
      for (int n=0;n<4;n++){
        float r = fmaxf(acc[n][q], 0.f);
        s0 += r*w2a[n]; s1 += r*w2b[n];
      }
      #pragma unroll
      for (int off=1; off<16; off<<=1){
        s0 += __shfl_xor(s0, off, 64);
        s1 += __shfl_xor(s1, off, 64);
      }
      if (col == 0){
        int b = blk*16 + hi*4 + q;
        float np0 = posg[(size_t)b*2]     + s0 + bp20;
        float np1 = posg[(size_t)b*2 + 1] + s1 + bp21;
        posg[(size_t)b*2]     = np0;
        posg[(size_t)b*2 + 1] = np1;
        out[((size_t)b*NSTEP + t)*2]     = np0;
        out[((size_t)b*NSTEP + t)*2 + 1] = np1;
      }
    }
  }
}

// ===================== fallback: R16 persistent kernel (proven) =====================
#define BBF 16
#define STAGEF(seq, bufi) do{ \
  const unsigned short* g_ = wsW + (size_t)(seq)*16384 + w*2048 + lane*8; \
  unsigned short* l_ = sh_stage + (size_t)(bufi)*16384 + w*2048; \
  __builtin_amdgcn_global_load_lds((const __attribute__((address_space(1))) void*)(g_       ), (__attribute__((address_space(3))) void*)(l_       ), 16,0,0); \
  __builtin_amdgcn_global_load_lds((const __attribute__((address_space(1))) void*)(g_ +  512), (__attribute__((address_space(3))) void*)(l_ +  512), 16,0,0); \
  __builtin_amdgcn_global_load_lds((const __attribute__((address_space(1))) void*)(g_ + 1024), (__attribute__((address_space(3))) void*)(l_ + 1024), 16,0,0); \
  __builtin_amdgcn_global_load_lds((const __attribute__((address_space(1))) void*)(g_ + 1536), (__attribute__((address_space(3))) void*)(l_ + 1536), 16,0,0); \
}while(0)
#define CHUNKF(cl, MI, HS) do{ \
  const int c_  = (MI)*16 + (cl); \
  const int s2_ = (c_+2) % 48; \
  asm volatile("s_waitcnt vmcnt(4)" ::: "memory"); \
  __builtin_amdgcn_s_barrier(); \
  __builtin_amdgcn_sched_barrier(0); \
  STAGEF(s2_, (c_+2)%3); \
  const unsigned short* sb_ = sh_stage + (size_t)(c_%3)*16384 + lane*8; \
  const int gI_ = (cl)>>2, kh_ = (cl)&3; \
  s8v aA_ = rdaf(HS, col, hi, 2*kh_+0); \
  s8v aB_ = rdaf(HS, col, hi, 2*kh_+1); \
  { s8v wf_ = *(const s8v*)(sb_ + (0*16 + (w*2+0))*512); acc[0][gI_] = MFMA16(aA_, wf_, acc[0][gI_]); } \
  { s8v wf_ = *(const s8v*)(sb_ + (0*16 + (w*2+1))*512); acc[1][gI_] = MFMA16(aA_, wf_, acc[1][gI_]); } \
  { s8v wf_ = *(const s8v*)(sb_ + (1*16 + (w*2+0))*512); acc[0][gI_] = MFMA16(aB_, wf_, acc[0][gI_]); } \
  { s8v wf_ = *(const s8v*)(sb_ + (1*16 + (w*2+1))*512); acc[1][gI_] = MFMA16(aB_, wf_, acc[1][gI_]); } \
}while(0)

__device__ __forceinline__ void wrh(unsigned short* lds, int b, int u, float v){
  lds[b*HN + (u ^ ((b&7)<<3))] = f2bf(v);
}
__device__ __forceinline__ s8v rdaf(const unsigned short* lds, int b, int hi, int kt){
  int blk = (kt*4 + hi) ^ (b & 7);
  return *(const s8v*)(lds + b*HN + blk*8);
}

__global__ __launch_bounds__(512, 1)
void traj_fb(const float* __restrict__ enc, const float* __restrict__ pos0,
             const float* __restrict__ ctx, const float* __restrict__ Wh,
             const float* __restrict__ bh,  const float* __restrict__ Wc,
             const float* __restrict__ bc,  const float* __restrict__ Wih0,
             const float* __restrict__ bih0,const float* __restrict__ bhh0,
             const float* __restrict__ bih1,const float* __restrict__ bhh1,
             const float* __restrict__ Wp2, const float* __restrict__ bp1,
             const float* __restrict__ bp2, const unsigned short* __restrict__ wsW,
             float* __restrict__ out)
{
  __shared__ unsigned short sh_stage[3*16384];
  __shared__ unsigned short sh_gx[BBF*1024];
  __shared__ unsigned short sh_h0u[BBF*HN];
  __shared__ unsigned short sh_h1u[BBF*HN];
  __shared__ float sh_pos[BBF][2];
  __shared__ float sh_red[4][BBF][2];

  const int tid  = threadIdx.x;
  const int gb0  = blockIdx.x * BBF;
  const int lane = tid & 63;
  const int w    = tid >> 6;
  const int col  = lane & 15;
  const int hi   = lane >> 4;
  float* sh_xf = (float*)sh_stage;

  { const float4* src = (const float4*)(enc + (size_t)gb0*DM);
    ((float4*)sh_xf)[tid] = src[tid]; }
  if (tid < BBF*2) ((float*)sh_pos)[tid] = pos0[(size_t)gb0*2 + tid];
  __syncthreads();
  {
    float* ctF = (float*)sh_gx;
    const int r = tid;
    float ah[BBF], ac[BBF];
    #pragma unroll
    for (int b=0;b<BBF;b++){ ah[b]=0.f; ac[b]=0.f; }
    const float4* whr = (const float4*)(Wh + (size_t)r*DM);
    const float4* wcr = (const float4*)(Wc + (size_t)r*DM);
    #pragma nounroll
    for (int kk=0; kk<DM/4; kk++){
      float4 w0 = whr[kk], w1 = wcr[kk];
      #pragma unroll
      for (int b=0;b<BBF;b++){
        float4 x = *(const float4*)&sh_xf[b*DM + kk*4];
        ah[b] += w0.x*x.x + w0.y*x.y + w0.z*x.z + w0.w*x.w;
        ac[b] += w1.x*x.x + w1.y*x.y + w1.z*x.z + w1.w*x.w;
      }
    }
    float bhv = bh[r], bcv = bc[r];
    if (r < HN){
      #pragma unroll
      for (int b=0;b<BBF;b++){ wrh(sh_h0u, b, r, ah[b]+bhv); ctF[(size_t)b*HN + r] = ac[b]+bcv; }
    } else {
      #pragma unroll
      for (int b=0;b<BBF;b++){ wrh(sh_h1u, b, r-HN, ah[b]+bhv); ctF[4096 + (size_t)b*HN + (r-HN)] = ac[b]+bcv; }
    }
  }
  __syncthreads();
  float c0r[2][4], c1r[2][4];
  {
    const float* ctF = (const float*)sh_gx;
    #pragma unroll
    for (int m=0;m<2;m++){
      int uu = (w*2+m)*16 + col;
      #pragma unroll
      for (int q=0;q<4;q++){
        int b = hi*4+q;
        c0r[m][q] = ctF[(size_t)b*HN + uu];
        c1r[m][q] = ctF[4096 + (size_t)b*HN + uu];
      }
    }
  }
  __syncthreads();
  { const float4* src = (const float4*)(ctx + (size_t)gb0*DM);
    ((float4*)sh_xf)[tid] = src[tid]; }
  __syncthreads();
  {
    float a0[BBF], a1[BBF];
    #pragma unroll
    for (int b=0;b<BBF;b++){ a0[b]=0.f; a1[b]=0.f; }
    const float2* wr0 = (const float2*)(Wih0 + (size_t)tid*130 + 2);
    const float2* wr1 = (const float2*)(Wih0 + (size_t)(tid+512)*130 + 2);
    #pragma nounroll
    for (int kk=0; kk<DM/2; kk++){
      float2 w0 = wr0[kk], w1 = wr1[kk];
      #pragma unroll
      for (int b=0;b<BBF;b++){
        float2 x = *(const float2*)&sh_xf[b*DM + kk*2];
        a0[b] += w0.x*x.x + w0.y*x.y;
        a1[b] += w1.x*x.x + w1.y*x.y;
      }
    }
    float cb0 = bih0[tid] + bhh0[tid];
    float cb1 = bih0[tid+512] + bhh0[tid+512];
    #pragma unroll
    for (int b=0;b<BBF;b++){
      sh_gx[(size_t)b*1024 + tid]       = f2bf(a0[b] + cb0);
      sh_gx[(size_t)b*1024 + tid + 512] = f2bf(a1[b] + cb1);
    }
  }
  float wpr[2][4][2]; float b1r[2][4];
  #pragma unroll
  for (int m=0;m<2;m++){
    int uu = (w*2+m)*16 + col;
    #pragma unroll
    for (int g=0;g<4;g++){
      int j = (g<<8) + uu;
      wpr[m][g][0] = Wih0[(size_t)j*130 + 0];
      wpr[m][g][1] = Wih0[(size_t)j*130 + 1];
      b1r[m][g]    = bih1[j] + bhh1[j];
    }
  }
  const float bp1p = bp1[(w&3)*16 + col];
  const float w20  = Wp2[(w&3)*16 + col];
  const float w21  = Wp2[64 + (w&3)*16 + col];
  const float bp20 = bp2[0], bp21 = bp2[1];
  const unsigned short* wTp = wsW + 786432 + lane*8;
  __syncthreads();
  STAGEF(0, 0);
  STAGEF(1, 1);
  #pragma nounroll
  for (int t=0; t<NSTEP; t++){
    f32x4 acc[2][4];
    #pragma unroll
    for (int m=0;m<2;m++){
      const int uu = (w*2+m)*16 + col;
      #pragma unroll
      for (int q=0;q<4;q++){
        float2 pp = *(const float2*)&sh_pos[hi*4+q][0];
        #pragma unroll
        for (int g=0;g<4;g++)
          acc[m][g][q] = bf2f(sh_gx[(size_t)(hi*4+q)*1024 + (g<<8) + uu])
                       + pp.x*wpr[m][g][0] + pp.y*wpr[m][g][1];
      }
    }
    #pragma unroll
    for (int cl=0; cl<16; cl++){ CHUNKF(cl, 0, sh_h0u); }
    __syncthreads();
    #pragma unroll
    for (int m=0;m<2;m++){
      int uu = (w*2+m)*16 + col;
      #pragma unroll
      for (int q=0;q<4;q++){
        float iv = sigm(acc[m][0][q]), fv = sigm(acc[m][1][q]);
        float gv = tanhx(acc[m][2][q]), ov = sigm(acc[m][3][q]);
        float cv = fv*c0r[m][q] + iv*gv;
        c0r[m][q] = cv;
        wrh(sh_h0u, hi*4+q, uu, ov*tanhx(cv));
      }
    }
    __syncthreads();
    #pragma unroll
    for (int m=0;m<2;m++)
      #pragma unroll
      for (int g=0;g<4;g++)
        #pragma unroll
        for (int q=0;q<4;q++)
          acc[m][g][q] = b1r[m][g];
    #pragma unroll
    for (int cl=0; cl<16; cl++){ CHUNKF(cl, 1, sh_h0u); }
    #pragma unroll
    for (int cl=0; cl<16; cl++){ CHUNKF(cl, 2, sh_h1u); }
    __syncthreads();
    #pragma unroll
    for (int m=0;m<2;m++){
      int uu = (w*2+m)*16 + col;
      #pragma unroll
      for (int q=0;q<4;q++){
        float iv = sigm(acc[m][0][q]), fv = sigm(acc[m][1][q]);
        float gv = tanhx(acc[m][2][q]), ov = sigm(acc[m][3][q]);
        float cv = fv*c1r[m][q] + iv*gv;
        c1r[m][q] = cv;
        wrh(sh_h1u, hi*4+q, uu, ov*tanhx(cv));
      }
    }
    __syncthreads();
    if (w < 4){
      f32x4 hp = {bp1p, bp1p, bp1p, bp1p};
      #pragma unroll
      for (int kt=0;kt<8;kt++){
        s8v a1n = rdaf(sh_h1u, col, hi, kt);
        s8v wfp = *(const s8v*)(wTp + (size_t)((w&3)*8+kt)*512);
        hp = MFMA16(a1n, wfp, hp);
      }
      #pragma unroll
      for (int q=0;q<4;q++){
        float r  = fmaxf(hp[q], 0.f);
        float s0 = r*w20, s1 = r*w21;
        #pragma unroll
        for (int off=1; off<16; off<<=1){
          s0 += __shfl_xor(s0, off, 64);
          s1 += __shfl_xor(s1, off, 64);
        }
        if (col == 0){ sh_red[w][hi*4+q][0] = s0; sh_red[w][hi*4+q][1] = s1; }
      }
    }
    __syncthreads();
    if (tid < BBF*2){
      int b = tid >> 1, d = tid & 1;
      float s = sh_red[0][b][d] + sh_red[1][b][d] + sh_red[2][b][d] + sh_red[3][b][d]
              + (d ? bp21 : bp20);
      float np = sh_pos[b][d] + s;
      sh_pos[b][d] = np;
      out[((size_t)(gb0+b)*NSTEP + t)*2 + d] = np;
    }
    __syncthreads();
  }
}

extern "C" void kernel_launch(void* const* d_in, const int* in_sizes, int n_in,
                              void* d_out, int out_size, void* d_ws, size_t ws_size,
                              hipStream_t stream) {
  const float* enc  = (const float*)d_in[0];
  const float* pos0 = (const float*)d_in[1];
  const float* ctx  = (const float*)d_in[2];
  const float* Wh   = (const float*)d_in[3];
  const float* bh   = (const float*)d_in[4];
  const float* Wc   = (const float*)d_in[5];
  const float* bc   = (const float*)d_in[6];
  const float* Wih0 = (const float*)d_in[7];
  const float* Whh0 = (const float*)d_in[8];
  const float* bih0 = (const float*)d_in[9];
  const float* bhh0 = (const float*)d_in[10];
  const float* Wih1 = (const float*)d_in[11];
  const float* Whh1 = (const float*)d_in[12];
  const float* bih1 = (const float*)d_in[13];
  const float* bhh1 = (const float*)d_in[14];
  const float* Wp1  = (const float*)d_in[15];
  const float* bp1  = (const float*)d_in[16];
  const float* Wp2  = (const float*)d_in[17];
  const float* bp2  = (const float*)d_in[18];
  float* out = (float*)d_out;
  unsigned short* wsW = (unsigned short*)d_ws;

  hipLaunchKernelGGL(repack, dim3(392), dim3(256), 0, stream,
                     Whh0, Wih1, Whh1, Wp1, wsW);

  if (ws_size >= (size_t)WS_NEED){
    unsigned short* h0a = (unsigned short*)((char*)d_ws + H0A_OFF);
    unsigned short* h0b = (unsigned short*)((char*)d_ws + H0B_OFF);
    unsigned short* h1a = (unsigned short*)((char*)d_ws + H1A_OFF);
    unsigned short* h1b = (unsigned short*)((char*)d_ws + H1B_OFF);
    unsigned short* gxg = (unsigned short*)((char*)d_ws + GX_OFF);
    float* c0g  = (float*)((char*)d_ws + C0_OFF);
    float* c1g  = (float*)((char*)d_ws + C1_OFF);
    float* posg = (float*)((char*)d_ws + POS_OFF);

    hipLaunchKernelGGL(k_init, dim3(256), dim3(512), 0, stream,
                       enc, pos0, ctx, Wh, bh, Wc, bc, Wih0, bih0, bhh0,
                       h0a, h1a, gxg, c0g, c1g, posg);

    for (int t = 0; t < NSTEP; t++){
      unsigned short* h0r = (t & 1) ? h0b : h0a;
      unsigned short* h0w = (t & 1) ? h0a : h0b;
      unsigned short* h1r = (t & 1) ? h1b : h1a;
      unsigned short* h1w = (t & 1) ? h1a : h1b;
      hipLaunchKernelGGL(k_layer0, dim3(256), dim3(256), 0, stream,
                         wsW, gxg, h0r, h0w, c0g, posg, Wih0);
      hipLaunchKernelGGL(k_layer1, dim3(256), dim3(256), 0, stream,
                         wsW, h0w, h1r, h1w, c1g, bih1, bhh1);
      hipLaunchKernelGGL(k_head, dim3(32), dim3(256), 0, stream,
                         wsW, h1w, posg, bp1, Wp2, bp2, out, t);
    }
  } else {
    hipLaunchKernelGGL(traj_fb, dim3(4096 / BBF), dim3(512), 0, stream,
                       enc, pos0, ctx, Wh, bh, Wc, bc, Wih0, bih0, bhh0,
                       bih1, bhh1, Wp2, bp1, bp2, wsW, out);
  }
}

// Round 18
// 2103.370 us; speedup vs baseline: 1.9603x; 1.4894x over previous
//
#include <hip/hip_runtime.h>

// TrajectoryDecoder: 2-layer LSTM (H=256), 45 steps, B=4096.
// R18: R17's multi-kernel GEMM tiling, tightened:
//  - k1/k2 grid 32 bt x 16 sl = 512 WGs (2/CU, 8 waves) -> latency hidden.
//  - k_head(t-1) folded into k_layer0(t): every WG recomputes the head for
//    its own 128 batches (butterfly leaves delta in all lanes); sl==0 WGs
//    write double-buffered pos + out[t-1]. One final k_head emits out[44].
//  - k_init dot loops unrolled (was latency-bound, 118us).
// 45x2+3 dispatches. State in d_ws; layouts unchanged from R17 (verified).
// mfma_f32_16x16x32_bf16: A row=lane&15(batch), k=(lane>>4)*8+j;
//   B col=lane&15(gate unit); C/D row=(lane>>4)*4+q, col=lane&15.

#define HN    256
#define DM    128
#define NSTEP 45

// ---- d_ws layout (bytes) ----
#define H0A_OFF  1605632ULL
#define HBUF_B   2097152ULL                 // 4096*256*2 bytes
#define H0B_OFF  (H0A_OFF + HBUF_B)
#define H1A_OFF  (H0B_OFF + HBUF_B)
#define H1B_OFF  (H1A_OFF + HBUF_B)
#define GX_OFF   (H1B_OFF + HBUF_B)         // gctx bf16 [256 blk][1024 row][16 b]
#define GX_B     8388608ULL
#define C0_OFF   (GX_OFF + GX_B)            // c0 fp32 [256 blk][256 u][16 b]
#define CB_B     4194304ULL
#define C1_OFF   (C0_OFF + CB_B)
#define POSA_OFF (C1_OFF + CB_B)            // pos fp32 [4096][2] (t even)
#define POSB_OFF (POSA_OFF + 32768ULL)      // pos fp32 [4096][2] (t odd)
#define WS_NEED  (POSB_OFF + 32768ULL)

typedef __attribute__((ext_vector_type(8))) short s8v;
typedef __attribute__((ext_vector_type(4))) float f32x4;

#define MFMA16(a,b,c) __builtin_amdgcn_mfma_f32_16x16x32_bf16((a),(b),(c),0,0,0)

__device__ __forceinline__ unsigned short f2bf(float f){
  union { float f; unsigned u; } x; x.f = f;
  unsigned r = x.u + 0x7fffu + ((x.u >> 16) & 1u);
  return (unsigned short)(r >> 16);
}
__device__ __forceinline__ float bf2f(unsigned short h){
  union { unsigned u; float f; } x; x.u = ((unsigned)h) << 16;
  return x.f;
}
__device__ __forceinline__ float sigm(float x){
  x = fminf(40.f, fmaxf(-40.f, x));
  return 1.f/(1.f + __expf(-x));
}
__device__ __forceinline__ float tanhx(float x){
  float xx = fminf(15.f, fmaxf(-15.f, x));
  float e = __expf(2.f*xx);
  return (e-1.f)/(e+1.f);
}

// h tile layout (verified): elem (blk, b, u) at
//   blk*4096 + (u>>5)*512 + ((b&15) + ((u>>3)&3)*16)*8 + (u&7)   [ushorts]
__device__ __forceinline__ void store_h(unsigned short* buf, int blk, int b, int u, float v){
  buf[(size_t)blk*4096 + (u>>5)*512 + ((b&15) + ((u>>3)&3)*16)*8 + (u&7)] = f2bf(v);
}
__device__ __forceinline__ s8v ld_af(const unsigned short* buf, int blk, int kt, int lane){
  return *(const s8v*)(buf + (size_t)blk*4096 + kt*512 + lane*8);
}

// ---- repack (unchanged, verified): fp32 -> bf16 B-frag tiles ----
__global__ void repack(const float* __restrict__ Whh0, const float* __restrict__ Wih1,
                       const float* __restrict__ Whh1, const float* __restrict__ Wp1,
                       unsigned short* __restrict__ dst){
  int gid  = blockIdx.x*256 + threadIdx.x;
  int lane = gid & 63;
  int tile = gid >> 6;
  const float* src; int row; size_t doff;
  int k0 = (lane>>4)*8;
  if (tile < 1536){
    int mi = tile / 512;
    int r  = tile % 512;
    int ut = r & 15;
    int kt = (r >> 4) & 7;
    int g  = r >> 7;
    src  = (mi==0) ? Whh0 : (mi==1) ? Wih1 : Whh1;
    row  = g*256 + ut*16 + (lane&15);
    k0  += kt*32;
    doff = (size_t)mi*262144 + (size_t)r*512 + lane*8;
  } else {
    int r2 = tile - 1536;
    int kt = r2 & 7, pt = r2 >> 3;
    src  = Wp1;
    row  = pt*16 + (lane&15);
    k0  += kt*32;
    doff = 786432 + (size_t)r2*512 + lane*8;
  }
  const float* s = src + (size_t)row*HN + k0;
  float4 a = *(const float4*)(s);
  float4 b = *(const float4*)(s+4);
  unsigned short* d = dst + doff;
  d[0]=f2bf(a.x); d[1]=f2bf(a.y); d[2]=f2bf(a.z); d[3]=f2bf(a.w);
  d[4]=f2bf(b.x); d[5]=f2bf(b.y); d[6]=f2bf(b.z); d[7]=f2bf(b.w);
}

// ===================== init: h/c/gctx/pos state =====================
__global__ __launch_bounds__(512, 1)
void k_init(const float* __restrict__ enc, const float* __restrict__ pos0,
            const float* __restrict__ ctx, const float* __restrict__ Wh,
            const float* __restrict__ bh,  const float* __restrict__ Wc,
            const float* __restrict__ bc,  const float* __restrict__ Wih0,
            const float* __restrict__ bih0,const float* __restrict__ bhh0,
            unsigned short* __restrict__ h0a, unsigned short* __restrict__ h1a,
            unsigned short* __restrict__ gxg,
            float* __restrict__ c0g, float* __restrict__ c1g,
            float* __restrict__ posg)
{
  __shared__ float sh_x[16*DM];   // 8KB
  const int tid = threadIdx.x;
  const int blk = blockIdx.x;     // 16 batches
  const int gb0 = blk*16;

  {
    const float4* src = (const float4*)(enc + (size_t)gb0*DM);
    ((float4*)sh_x)[tid] = src[tid];
  }
  if (tid < 32) posg[(size_t)gb0*2 + tid] = pos0[(size_t)gb0*2 + tid];
  __syncthreads();

  {
    const int r = tid;
    float ah[16], ac[16];
    #pragma unroll
    for (int b=0;b<16;b++){ ah[b]=0.f; ac[b]=0.f; }
    const float4* whr = (const float4*)(Wh + (size_t)r*DM);
    const float4* wcr = (const float4*)(Wc + (size_t)r*DM);
    #pragma unroll 4
    for (int kk=0; kk<DM/4; kk++){
      float4 w0 = whr[kk], w1 = wcr[kk];
      #pragma unroll
      for (int b=0;b<16;b++){
        float4 x = *(const float4*)&sh_x[b*DM + kk*4];
        ah[b] += w0.x*x.x + w0.y*x.y + w0.z*x.z + w0.w*x.w;
        ac[b] += w1.x*x.x + w1.y*x.y + w1.z*x.z + w1.w*x.w;
      }
    }
    float bhv = bh[r], bcv = bc[r];
    if (r < HN){
      #pragma unroll
      for (int b=0;b<16;b++){
        store_h(h0a, blk, b, r, ah[b] + bhv);
        c0g[(size_t)blk*4096 + r*16 + b] = ac[b] + bcv;
      }
    } else {
      #pragma unroll
      for (int b=0;b<16;b++){
        store_h(h1a, blk, b, r-HN, ah[b] + bhv);
        c1g[(size_t)blk*4096 + (r-HN)*16 + b] = ac[b] + bcv;
      }
    }
  }
  __syncthreads();

  {
    const float4* src = (const float4*)(ctx + (size_t)gb0*DM);
    ((float4*)sh_x)[tid] = src[tid];
  }
  __syncthreads();

  {
    float a0[16], a1[16];
    #pragma unroll
    for (int b=0;b<16;b++){ a0[b]=0.f; a1[b]=0.f; }
    const float2* wr0 = (const float2*)(Wih0 + (size_t)tid*130 + 2);
    const float2* wr1 = (const float2*)(Wih0 + (size_t)(tid+512)*130 + 2);
    #pragma unroll 4
    for (int kk=0; kk<DM/2; kk++){
      float2 w0 = wr0[kk], w1 = wr1[kk];
      #pragma unroll
      for (int b=0;b<16;b++){
        float2 x = *(const float2*)&sh_x[b*DM + kk*2];
        a0[b] += w0.x*x.x + w0.y*x.y;
        a1[b] += w1.x*x.x + w1.y*x.y;
      }
    }
    float cb0 = bih0[tid]     + bhh0[tid];
    float cb1 = bih0[tid+512] + bhh0[tid+512];
    #pragma unroll
    for (int b=0;b<16;b++){
      gxg[(size_t)blk*16384 + (size_t)tid*16 + b]       = f2bf(a0[b] + cb0);
      gxg[(size_t)blk*16384 + (size_t)(tid+512)*16 + b] = f2bf(a1[b] + cb1);
    }
  }
}

// ===================== k1: head(t-1) + layer0 gates + cell =====================
// grid: bt(0..31)*16 + sl(0..15); TPB 256 (4 waves). M=128, N=64, K=256.
__global__ __launch_bounds__(256, 2)
void k_layer0(const unsigned short* __restrict__ wsW,
              const unsigned short* __restrict__ gxg,
              const unsigned short* __restrict__ h0rd,
              unsigned short* __restrict__ h0wr,
              const unsigned short* __restrict__ h1prev,
              float* __restrict__ c0g,
              const float* __restrict__ posRd,
              float* __restrict__ posWr,
              const float* __restrict__ Wih0,
              const float* __restrict__ bp1,
              const float* __restrict__ Wp2,
              const float* __restrict__ bp2,
              float* __restrict__ out, int t)
{
  const int tid  = threadIdx.x;
  const int lane = tid & 63;
  const int w    = tid >> 6;       // 0..3
  const int col  = lane & 15;
  const int hi   = lane >> 4;
  const int bt   = blockIdx.x >> 4;
  const int sl   = blockIdx.x & 15;

  const int blk0 = bt*8 + w*2;

  // ---- pos for this wave's 2 blocks (fold head(t-1) when t>0) ----
  float p0[2][4], p1[2][4];
  if (t > 0){
    float bpv[4], w2a[4], w2b[4];
    #pragma unroll
    for (int n=0;n<4;n++){
      bpv[n] = bp1[n*16 + col];
      w2a[n] = Wp2[n*16 + col];
      w2b[n] = Wp2[64 + n*16 + col];
    }
    const float bp20 = bp2[0], bp21 = bp2[1];
    #pragma unroll
    for (int m2=0;m2<2;m2++){
      const int blk = blk0 + m2;
      f32x4 hp[4];
      #pragma unroll
      for (int n=0;n<4;n++)
        #pragma unroll
        for (int q=0;q<4;q++) hp[n][q] = bpv[n];
      #pragma unroll
      for (int kt=0;kt<8;kt++){
        s8v a = ld_af(h1prev, blk, kt, lane);
        #pragma unroll
        for (int n=0;n<4;n++){
          s8v bf = *(const s8v*)(wsW + 786432 + (size_t)(n*8+kt)*512 + lane*8);
          hp[n] = MFMA16(a, bf, hp[n]);
        }
      }
      #pragma unroll
      for (int q=0;q<4;q++){
        float s0 = 0.f, s1 = 0.f;
        #pragma unroll
        for (int n=0;n<4;n++){
          float r = fmaxf(hp[n][q], 0.f);
          s0 += r*w2a[n]; s1 += r*w2b[n];
        }
        #pragma unroll
        for (int off=1; off<16; off<<=1){
          s0 += __shfl_xor(s0, off, 64);
          s1 += __shfl_xor(s1, off, 64);
        }
        int b = blk*16 + hi*4 + q;
        float2 pp = *(const float2*)(posRd + (size_t)b*2);
        float np0 = pp.x + s0 + bp20;
        float np1 = pp.y + s1 + bp21;
        p0[m2][q] = np0; p1[m2][q] = np1;
        if (sl == 0 && col == 0){
          posWr[(size_t)b*2]     = np0;
          posWr[(size_t)b*2 + 1] = np1;
          out[((size_t)b*NSTEP + (t-1))*2]     = np0;
          out[((size_t)b*NSTEP + (t-1))*2 + 1] = np1;
        }
      }
    }
  } else {
    #pragma unroll
    for (int m2=0;m2<2;m2++)
      #pragma unroll
      for (int q=0;q<4;q++){
        float2 pp = *(const float2*)(posRd + (size_t)((blk0+m2)*16 + hi*4 + q)*2);
        p0[m2][q] = pp.x; p1[m2][q] = pp.y;
      }
  }

  // ---- layer0 gates: N=64 rows (4 gates x unit-tile sl) ----
  float wpr[4][2];
  #pragma unroll
  for (int g=0;g<4;g++){
    int row = g*256 + sl*16 + col;
    wpr[g][0] = Wih0[(size_t)row*130 + 0];
    wpr[g][1] = Wih0[(size_t)row*130 + 1];
  }

  f32x4 acc[2][4];
  #pragma unroll
  for (int m2=0;m2<2;m2++){
    const int blk = blk0 + m2;
    #pragma unroll
    for (int g=0;g<4;g++){
      int row = g*256 + sl*16 + col;
      const unsigned short* gp = gxg + (size_t)blk*16384 + (size_t)row*16 + hi*4;
      #pragma unroll
      for (int q=0;q<4;q++)
        acc[m2][g][q] = bf2f(gp[q]) + p0[m2][q]*wpr[g][0] + p1[m2][q]*wpr[g][1];
    }
  }

  #pragma unroll
  for (int kt=0;kt<8;kt++){
    s8v a0 = ld_af(h0rd, blk0,   kt, lane);
    s8v a1 = ld_af(h0rd, blk0+1, kt, lane);
    #pragma unroll
    for (int g=0;g<4;g++){
      const int r = (g*8 + kt)*16 + sl;
      s8v bf = *(const s8v*)(wsW + (size_t)r*512 + lane*8);
      acc[0][g] = MFMA16(a0, bf, acc[0][g]);
      acc[1][g] = MFMA16(a1, bf, acc[1][g]);
    }
  }

  // ---- cell0: unit u = sl*16 + col ----
  const int u = sl*16 + col;
  #pragma unroll
  for (int m2=0;m2<2;m2++){
    const int blk = blk0 + m2;
    float* cp = c0g + (size_t)blk*4096 + u*16 + hi*4;
    float4 cold = *(const float4*)cp;
    float4 cnew;
    #pragma unroll
    for (int q=0;q<4;q++){
      float iv = sigm(acc[m2][0][q]);
      float fv = sigm(acc[m2][1][q]);
      float gv = tanhx(acc[m2][2][q]);
      float ov = sigm(acc[m2][3][q]);
      float cv = fv*((&cold.x)[q]) + iv*gv;
      (&cnew.x)[q] = cv;
      store_h(h0wr, blk, hi*4+q, u, ov*tanhx(cv));
    }
    *(float4*)cp = cnew;
  }
}

// ===================== k2: layer1 gates + cell =====================
__global__ __launch_bounds__(256, 2)
void k_layer1(const unsigned short* __restrict__ wsW,
              const unsigned short* __restrict__ h0n,
              const unsigned short* __restrict__ h1rd,
              unsigned short* __restrict__ h1wr,
              float* __restrict__ c1g,
              const float* __restrict__ bih1,
              const float* __restrict__ bhh1)
{
  const int tid  = threadIdx.x;
  const int lane = tid & 63;
  const int w    = tid >> 6;
  const int col  = lane & 15;
  const int hi   = lane >> 4;
  const int bt   = blockIdx.x >> 4;
  const int sl   = blockIdx.x & 15;

  const int blk0 = bt*8 + w*2;

  f32x4 acc[2][4];
  #pragma unroll
  for (int g=0;g<4;g++){
    int row = g*256 + sl*16 + col;
    float bv = bih1[row] + bhh1[row];
    #pragma unroll
    for (int q=0;q<4;q++){ acc[0][g][q] = bv; acc[1][g][q] = bv; }
  }

  #pragma unroll
  for (int kt=0;kt<8;kt++){
    s8v a0 = ld_af(h0n, blk0,   kt, lane);
    s8v a1 = ld_af(h0n, blk0+1, kt, lane);
    #pragma unroll
    for (int g=0;g<4;g++){
      const int r = (g*8 + kt)*16 + sl;
      s8v bf = *(const s8v*)(wsW + 262144 + (size_t)r*512 + lane*8);
      acc[0][g] = MFMA16(a0, bf, acc[0][g]);
      acc[1][g] = MFMA16(a1, bf, acc[1][g]);
    }
  }
  #pragma unroll
  for (int kt=0;kt<8;kt++){
    s8v a0 = ld_af(h1rd, blk0,   kt, lane);
    s8v a1 = ld_af(h1rd, blk0+1, kt, lane);
    #pragma unroll
    for (int g=0;g<4;g++){
      const int r = (g*8 + kt)*16 + sl;
      s8v bf = *(const s8v*)(wsW + 524288 + (size_t)r*512 + lane*8);
      acc[0][g] = MFMA16(a0, bf, acc[0][g]);
      acc[1][g] = MFMA16(a1, bf, acc[1][g]);
    }
  }

  const int u = sl*16 + col;
  #pragma unroll
  for (int m2=0;m2<2;m2++){
    const int blk = blk0 + m2;
    float* cp = c1g + (size_t)blk*4096 + u*16 + hi*4;
    float4 cold = *(const float4*)cp;
    float4 cnew;
    #pragma unroll
    for (int q=0;q<4;q++){
      float iv = sigm(acc[m2][0][q]);
      float fv = sigm(acc[m2][1][q]);
      float gv = tanhx(acc[m2][2][q]);
      float ov = sigm(acc[m2][3][q]);
      float cv = fv*((&cold.x)[q]) + iv*gv;
      (&cnew.x)[q] = cv;
      store_h(h1wr, blk, hi*4+q, u, ov*tanhx(cv));
    }
    *(float4*)cp = cnew;
  }
}

// ===================== k_head: final step's out only =====================
__global__ __launch_bounds__(256, 2)
void k_head(const unsigned short* __restrict__ wsW,
            const unsigned short* __restrict__ h1n,
            const float* __restrict__ posRd,
            const float* __restrict__ bp1,
            const float* __restrict__ Wp2,
            const float* __restrict__ bp2,
            float* __restrict__ out, int t)
{
  const int tid  = threadIdx.x;
  const int lane = tid & 63;
  const int w    = tid >> 6;
  const int col  = lane & 15;
  const int hi   = lane >> 4;
  const int bt   = blockIdx.x;

  float bpv[4], w2a[4], w2b[4];
  #pragma unroll
  for (int n=0;n<4;n++){
    bpv[n] = bp1[n*16 + col];
    w2a[n] = Wp2[n*16 + col];
    w2b[n] = Wp2[64 + n*16 + col];
  }
  const float bp20 = bp2[0], bp21 = bp2[1];

  #pragma unroll
  for (int m2=0;m2<2;m2++){
    const int blk = bt*8 + w*2 + m2;
    f32x4 acc[4];
    #pragma unroll
    for (int n=0;n<4;n++)
      #pragma unroll
      for (int q=0;q<4;q++) acc[n][q] = bpv[n];
    #pragma unroll
    for (int kt=0;kt<8;kt++){
      s8v a = ld_af(h1n, blk, kt, lane);
      #pragma unroll
      for (int n=0;n<4;n++){
        s8v bf = *(const s8v*)(wsW + 786432 + (size_t)(n*8+kt)*512 + lane*8);
        acc[n] = MFMA16(a, bf, acc[n]);
      }
    }
    #pragma unroll
    for (int q=0;q<4;q++){
      float s0 = 0.f, s1 = 0.f;
      #pragma unroll
      for (int n=0;n<4;n++){
        float r = fmaxf(acc[n][q], 0.f);
        s0 += r*w2a[n]; s1 += r*w2b[n];
      }
      #pragma unroll
      for (int off=1; off<16; off<<=1){
        s0 += __shfl_xor(s0, off, 64);
        s1 += __shfl_xor(s1, off, 64);
      }
      if (col == 0){
        int b = blk*16 + hi*4 + q;
        out[((size_t)b*NSTEP + t)*2]     = posRd[(size_t)b*2]     + s0 + bp20;
        out[((size_t)b*NSTEP + t)*2 + 1] = posRd[(size_t)b*2 + 1] + s1 + bp21;
      }
    }
  }
}

extern "C" void kernel_launch(void* const* d_in, const int* in_sizes, int n_in,
                              void* d_out, int out_size, void* d_ws, size_t ws_size,
                              hipStream_t stream) {
  const float* enc  = (const float*)d_in[0];
  const float* pos0 = (const float*)d_in[1];
  const float* ctx  = (const float*)d_in[2];
  const float* Wh   = (const float*)d_in[3];
  const float* bh   = (const float*)d_in[4];
  const float* Wc   = (const float*)d_in[5];
  const float* bc   = (const float*)d_in[6];
  const float* Wih0 = (const float*)d_in[7];
  const float* Whh0 = (const float*)d_in[8];
  const float* bih0 = (const float*)d_in[9];
  const float* bhh0 = (const float*)d_in[10];
  const float* Wih1 = (const float*)d_in[11];
  const float* Whh1 = (const float*)d_in[12];
  const float* bih1 = (const float*)d_in[13];
  const float* bhh1 = (const float*)d_in[14];
  const float* Wp1  = (const float*)d_in[15];
  const float* bp1  = (const float*)d_in[16];
  const float* Wp2  = (const float*)d_in[17];
  const float* bp2  = (const float*)d_in[18];
  float* out = (float*)d_out;
  unsigned short* wsW = (unsigned short*)d_ws;

  unsigned short* h0a = (unsigned short*)((char*)d_ws + H0A_OFF);
  unsigned short* h0b = (unsigned short*)((char*)d_ws + H0B_OFF);
  unsigned short* h1a = (unsigned short*)((char*)d_ws + H1A_OFF);
  unsigned short* h1b = (unsigned short*)((char*)d_ws + H1B_OFF);
  unsigned short* gxg = (unsigned short*)((char*)d_ws + GX_OFF);
  float* c0g  = (float*)((char*)d_ws + C0_OFF);
  float* c1g  = (float*)((char*)d_ws + C1_OFF);
  float* posA = (float*)((char*)d_ws + POSA_OFF);   // pos_t, t even
  float* posB = (float*)((char*)d_ws + POSB_OFF);   // pos_t, t odd

  hipLaunchKernelGGL(repack, dim3(392), dim3(256), 0, stream,
                     Whh0, Wih1, Whh1, Wp1, wsW);

  hipLaunchKernelGGL(k_init, dim3(256), dim3(512), 0, stream,
                     enc, pos0, ctx, Wh, bh, Wc, bc, Wih0, bih0, bhh0,
                     h0a, h1a, gxg, c0g, c1g, posA);

  unsigned short* h1prev = h1a;   // unused at t=0
  for (int t = 0; t < NSTEP; t++){
    unsigned short* h0r = (t & 1) ? h0b : h0a;
    unsigned short* h0w = (t & 1) ? h0a : h0b;
    unsigned short* h1r = (t & 1) ? h1b : h1a;
    unsigned short* h1w = (t & 1) ? h1a : h1b;
    float* pr = (t & 1) ? posB : posA;   // pos_t lives in buf[t&1]
    float* pw = (t & 1) ? posA : posB;   // scratch: k1 writes pos_t to buf[t&1]...

    // pos_t is computed inside k_layer0(t) from pos_{t-1} (buf[(t-1)&1]) and
    // h1prev; it is written to buf[t&1] for the NEXT step's read.
    float* posRead  = (t == 0) ? posA : ((t & 1) ? posA : posB); // pos_{t-1}
    float* posWrite = (t & 1) ? posB : posA;                      // pos_t
    (void)pr; (void)pw;

    hipLaunchKernelGGL(k_layer0, dim3(512), dim3(256), 0, stream,
                       wsW, gxg, h0r, h0w, h1prev, c0g,
                       posRead, posWrite, Wih0, bp1, Wp2, bp2, out, t);
    hipLaunchKernelGGL(k_layer1, dim3(512), dim3(256), 0, stream,
                       wsW, h0w, h1r, h1w, c1g, bih1, bhh1);
    h1prev = h1w;
  }
  // final out[44] from h1(44) and pos_44 (buf[44&1] = posA)
  hipLaunchKernelGGL(k_head, dim3(32), dim3(256), 0, stream,
                     wsW, h1prev, posA, bp1, Wp2, bp2, out, NSTEP-1);
}

// Round 19
// 1839.831 us; speedup vs baseline: 2.2411x; 1.1432x over previous
//
#include <hip/hip_runtime.h>

// TrajectoryDecoder: 2-layer LSTM (H=256), 45 steps, B=4096.
// R19: R18's 2-dispatch/step structure with fatter WGs: k1/k2 grid
// 32 bt x 8 sl = 256 WGs x 512 thr (1/CU, 8 waves), M=128 x N=128.
// Per-CU bytes/dispatch drop 384->256KB at equal wave count; head
// redundancy halves. Wave w = (wb<<1)|wh: wb in 0..3 picks 2 blocks,
// wh in 0..1 picks the 16-unit half of the WG's 32-unit slice.
// Everything else (repack, h-tile layout, head-fold into k1,
// double-buffered pos) unchanged from R18 (verified).
// mfma_f32_16x16x32_bf16: A row=lane&15(batch), k=(lane>>4)*8+j;
//   B col=lane&15(gate unit); C/D row=(lane>>4)*4+q, col=lane&15.

#define HN    256
#define DM    128
#define NSTEP 45

// ---- d_ws layout (bytes) ----
#define H0A_OFF  1605632ULL
#define HBUF_B   2097152ULL                 // 4096*256*2 bytes
#define H0B_OFF  (H0A_OFF + HBUF_B)
#define H1A_OFF  (H0B_OFF + HBUF_B)
#define H1B_OFF  (H1A_OFF + HBUF_B)
#define GX_OFF   (H1B_OFF + HBUF_B)         // gctx bf16 [256 blk][1024 row][16 b]
#define GX_B     8388608ULL
#define C0_OFF   (GX_OFF + GX_B)            // c0 fp32 [256 blk][256 u][16 b]
#define CB_B     4194304ULL
#define C1_OFF   (C0_OFF + CB_B)
#define POSA_OFF (C1_OFF + CB_B)
#define POSB_OFF (POSA_OFF + 32768ULL)
#define WS_NEED  (POSB_OFF + 32768ULL)

typedef __attribute__((ext_vector_type(8))) short s8v;
typedef __attribute__((ext_vector_type(4))) float f32x4;

#define MFMA16(a,b,c) __builtin_amdgcn_mfma_f32_16x16x32_bf16((a),(b),(c),0,0,0)

__device__ __forceinline__ unsigned short f2bf(float f){
  union { float f; unsigned u; } x; x.f = f;
  unsigned r = x.u + 0x7fffu + ((x.u >> 16) & 1u);
  return (unsigned short)(r >> 16);
}
__device__ __forceinline__ float bf2f(unsigned short h){
  union { unsigned u; float f; } x; x.u = ((unsigned)h) << 16;
  return x.f;
}
__device__ __forceinline__ float sigm(float x){
  x = fminf(40.f, fmaxf(-40.f, x));
  return 1.f/(1.f + __expf(-x));
}
__device__ __forceinline__ float tanhx(float x){
  float xx = fminf(15.f, fmaxf(-15.f, x));
  float e = __expf(2.f*xx);
  return (e-1.f)/(e+1.f);
}

// h tile layout (verified): elem (blk, b, u) at
//   blk*4096 + (u>>5)*512 + ((b&15) + ((u>>3)&3)*16)*8 + (u&7)   [ushorts]
__device__ __forceinline__ void store_h(unsigned short* buf, int blk, int b, int u, float v){
  buf[(size_t)blk*4096 + (u>>5)*512 + ((b&15) + ((u>>3)&3)*16)*8 + (u&7)] = f2bf(v);
}
__device__ __forceinline__ s8v ld_af(const unsigned short* buf, int blk, int kt, int lane){
  return *(const s8v*)(buf + (size_t)blk*4096 + kt*512 + lane*8);
}

// ---- repack (unchanged, verified): fp32 -> bf16 B-frag tiles ----
__global__ void repack(const float* __restrict__ Whh0, const float* __restrict__ Wih1,
                       const float* __restrict__ Whh1, const float* __restrict__ Wp1,
                       unsigned short* __restrict__ dst){
  int gid  = blockIdx.x*256 + threadIdx.x;
  int lane = gid & 63;
  int tile = gid >> 6;
  const float* src; int row; size_t doff;
  int k0 = (lane>>4)*8;
  if (tile < 1536){
    int mi = tile / 512;
    int r  = tile % 512;
    int ut = r & 15;
    int kt = (r >> 4) & 7;
    int g  = r >> 7;
    src  = (mi==0) ? Whh0 : (mi==1) ? Wih1 : Whh1;
    row  = g*256 + ut*16 + (lane&15);
    k0  += kt*32;
    doff = (size_t)mi*262144 + (size_t)r*512 + lane*8;
  } else {
    int r2 = tile - 1536;
    int kt = r2 & 7, pt = r2 >> 3;
    src  = Wp1;
    row  = pt*16 + (lane&15);
    k0  += kt*32;
    doff = 786432 + (size_t)r2*512 + lane*8;
  }
  const float* s = src + (size_t)row*HN + k0;
  float4 a = *(const float4*)(s);
  float4 b = *(const float4*)(s+4);
  unsigned short* d = dst + doff;
  d[0]=f2bf(a.x); d[1]=f2bf(a.y); d[2]=f2bf(a.z); d[3]=f2bf(a.w);
  d[4]=f2bf(b.x); d[5]=f2bf(b.y); d[6]=f2bf(b.z); d[7]=f2bf(b.w);
}

// ===================== init: h/c/gctx/pos state =====================
__global__ __launch_bounds__(512, 1)
void k_init(const float* __restrict__ enc, const float* __restrict__ pos0,
            const float* __restrict__ ctx, const float* __restrict__ Wh,
            const float* __restrict__ bh,  const float* __restrict__ Wc,
            const float* __restrict__ bc,  const float* __restrict__ Wih0,
            const float* __restrict__ bih0,const float* __restrict__ bhh0,
            unsigned short* __restrict__ h0a, unsigned short* __restrict__ h1a,
            unsigned short* __restrict__ gxg,
            float* __restrict__ c0g, float* __restrict__ c1g,
            float* __restrict__ posg)
{
  __shared__ float sh_x[16*DM];
  const int tid = threadIdx.x;
  const int blk = blockIdx.x;
  const int gb0 = blk*16;

  {
    const float4* src = (const float4*)(enc + (size_t)gb0*DM);
    ((float4*)sh_x)[tid] = src[tid];
  }
  if (tid < 32) posg[(size_t)gb0*2 + tid] = pos0[(size_t)gb0*2 + tid];
  __syncthreads();

  {
    const int r = tid;
    float ah[16], ac[16];
    #pragma unroll
    for (int b=0;b<16;b++){ ah[b]=0.f; ac[b]=0.f; }
    const float4* whr = (const float4*)(Wh + (size_t)r*DM);
    const float4* wcr = (const float4*)(Wc + (size_t)r*DM);
    #pragma unroll 4
    for (int kk=0; kk<DM/4; kk++){
      float4 w0 = whr[kk], w1 = wcr[kk];
      #pragma unroll
      for (int b=0;b<16;b++){
        float4 x = *(const float4*)&sh_x[b*DM + kk*4];
        ah[b] += w0.x*x.x + w0.y*x.y + w0.z*x.z + w0.w*x.w;
        ac[b] += w1.x*x.x + w1.y*x.y + w1.z*x.z + w1.w*x.w;
      }
    }
    float bhv = bh[r], bcv = bc[r];
    if (r < HN){
      #pragma unroll
      for (int b=0;b<16;b++){
        store_h(h0a, blk, b, r, ah[b] + bhv);
        c0g[(size_t)blk*4096 + r*16 + b] = ac[b] + bcv;
      }
    } else {
      #pragma unroll
      for (int b=0;b<16;b++){
        store_h(h1a, blk, b, r-HN, ah[b] + bhv);
        c1g[(size_t)blk*4096 + (r-HN)*16 + b] = ac[b] + bcv;
      }
    }
  }
  __syncthreads();

  {
    const float4* src = (const float4*)(ctx + (size_t)gb0*DM);
    ((float4*)sh_x)[tid] = src[tid];
  }
  __syncthreads();

  {
    float a0[16], a1[16];
    #pragma unroll
    for (int b=0;b<16;b++){ a0[b]=0.f; a1[b]=0.f; }
    const float2* wr0 = (const float2*)(Wih0 + (size_t)tid*130 + 2);
    const float2* wr1 = (const float2*)(Wih0 + (size_t)(tid+512)*130 + 2);
    #pragma unroll 4
    for (int kk=0; kk<DM/2; kk++){
      float2 w0 = wr0[kk], w1 = wr1[kk];
      #pragma unroll
      for (int b=0;b<16;b++){
        float2 x = *(const float2*)&sh_x[b*DM + kk*2];
        a0[b] += w0.x*x.x + w0.y*x.y;
        a1[b] += w1.x*x.x + w1.y*x.y;
      }
    }
    float cb0 = bih0[tid]     + bhh0[tid];
    float cb1 = bih0[tid+512] + bhh0[tid+512];
    #pragma unroll
    for (int b=0;b<16;b++){
      gxg[(size_t)blk*16384 + (size_t)tid*16 + b]       = f2bf(a0[b] + cb0);
      gxg[(size_t)blk*16384 + (size_t)(tid+512)*16 + b] = f2bf(a1[b] + cb1);
    }
  }
}

// ===================== k1: head(t-1) + layer0 gates + cell =====================
// grid: bt(0..31)*8 + sl(0..7); TPB 512 (8 waves: w=(wb<<1)|wh).
// Wave: blocks blk0=bt*8+wb*2 (+1); rows g*256 + sl*32 + wh*16 + col.
__global__ __launch_bounds__(512, 1)
void k_layer0(const unsigned short* __restrict__ wsW,
              const unsigned short* __restrict__ gxg,
              const unsigned short* __restrict__ h0rd,
              unsigned short* __restrict__ h0wr,
              const unsigned short* __restrict__ h1prev,
              float* __restrict__ c0g,
              const float* __restrict__ posRd,
              float* __restrict__ posWr,
              const float* __restrict__ Wih0,
              const float* __restrict__ bp1,
              const float* __restrict__ Wp2,
              const float* __restrict__ bp2,
              float* __restrict__ out, int t)
{
  const int tid  = threadIdx.x;
  const int lane = tid & 63;
  const int w    = tid >> 6;       // 0..7
  const int wb   = w >> 1;         // 0..3 block-pair
  const int wh   = w & 1;          // 0..1 unit half
  const int col  = lane & 15;
  const int hi   = lane >> 4;
  const int bt   = blockIdx.x >> 3;
  const int sl   = blockIdx.x & 7;

  const int blk0 = bt*8 + wb*2;
  const int ut   = sl*2 + wh;      // unit-tile 0..15
  const int u    = ut*16 + col;    // owned unit

  // ---- pos for this wave's 2 blocks (fold head(t-1) when t>0) ----
  float p0[2][4], p1[2][4];
  if (t > 0){
    float bpv[4], w2a[4], w2b[4];
    #pragma unroll
    for (int n=0;n<4;n++){
      bpv[n] = bp1[n*16 + col];
      w2a[n] = Wp2[n*16 + col];
      w2b[n] = Wp2[64 + n*16 + col];
    }
    const float bp20 = bp2[0], bp21 = bp2[1];
    #pragma unroll
    for (int m2=0;m2<2;m2++){
      const int blk = blk0 + m2;
      f32x4 hp[4];
      #pragma unroll
      for (int n=0;n<4;n++)
        #pragma unroll
        for (int q=0;q<4;q++) hp[n][q] = bpv[n];
      #pragma unroll
      for (int kt=0;kt<8;kt++){
        s8v a = ld_af(h1prev, blk, kt, lane);
        #pragma unroll
        for (int n=0;n<4;n++){
          s8v bf = *(const s8v*)(wsW + 786432 + (size_t)(n*8+kt)*512 + lane*8);
          hp[n] = MFMA16(a, bf, hp[n]);
        }
      }
      #pragma unroll
      for (int q=0;q<4;q++){
        float s0 = 0.f, s1 = 0.f;
        #pragma unroll
        for (int n=0;n<4;n++){
          float r = fmaxf(hp[n][q], 0.f);
          s0 += r*w2a[n]; s1 += r*w2b[n];
        }
        #pragma unroll
        for (int off=1; off<16; off<<=1){
          s0 += __shfl_xor(s0, off, 64);
          s1 += __shfl_xor(s1, off, 64);
        }
        int b = blk*16 + hi*4 + q;
        float2 pp = *(const float2*)(posRd + (size_t)b*2);
        float np0 = pp.x + s0 + bp2[0];
        float np1 = pp.y + s1 + bp2[1];
        (void)bp20; (void)bp21;
        p0[m2][q] = np0; p1[m2][q] = np1;
        if (sl == 0 && wh == 0 && col == 0){
          posWr[(size_t)b*2]     = np0;
          posWr[(size_t)b*2 + 1] = np1;
          out[((size_t)b*NSTEP + (t-1))*2]     = np0;
          out[((size_t)b*NSTEP + (t-1))*2 + 1] = np1;
        }
      }
    }
  } else {
    #pragma unroll
    for (int m2=0;m2<2;m2++)
      #pragma unroll
      for (int q=0;q<4;q++){
        float2 pp = *(const float2*)(posRd + (size_t)((blk0+m2)*16 + hi*4 + q)*2);
        p0[m2][q] = pp.x; p1[m2][q] = pp.y;
      }
  }

  // ---- layer0 gates: N=64 rows (4 gates x unit-tile ut) ----
  float wpr[4][2];
  #pragma unroll
  for (int g=0;g<4;g++){
    int row = g*256 + u;
    wpr[g][0] = Wih0[(size_t)row*130 + 0];
    wpr[g][1] = Wih0[(size_t)row*130 + 1];
  }

  f32x4 acc[2][4];
  #pragma unroll
  for (int m2=0;m2<2;m2++){
    const int blk = blk0 + m2;
    #pragma unroll
    for (int g=0;g<4;g++){
      int row = g*256 + u;
      const unsigned short* gp = gxg + (size_t)blk*16384 + (size_t)row*16 + hi*4;
      #pragma unroll
      for (int q=0;q<4;q++)
        acc[m2][g][q] = bf2f(gp[q]) + p0[m2][q]*wpr[g][0] + p1[m2][q]*wpr[g][1];
    }
  }

  #pragma unroll
  for (int kt=0;kt<8;kt++){
    s8v a0 = ld_af(h0rd, blk0,   kt, lane);
    s8v a1 = ld_af(h0rd, blk0+1, kt, lane);
    #pragma unroll
    for (int g=0;g<4;g++){
      const int r = (g*8 + kt)*16 + ut;
      s8v bf = *(const s8v*)(wsW + (size_t)r*512 + lane*8);
      acc[0][g] = MFMA16(a0, bf, acc[0][g]);
      acc[1][g] = MFMA16(a1, bf, acc[1][g]);
    }
  }

  // ---- cell0 ----
  #pragma unroll
  for (int m2=0;m2<2;m2++){
    const int blk = blk0 + m2;
    float* cp = c0g + (size_t)blk*4096 + u*16 + hi*4;
    float4 cold = *(const float4*)cp;
    float4 cnew;
    #pragma unroll
    for (int q=0;q<4;q++){
      float iv = sigm(acc[m2][0][q]);
      float fv = sigm(acc[m2][1][q]);
      float gv = tanhx(acc[m2][2][q]);
      float ov = sigm(acc[m2][3][q]);
      float cv = fv*((&cold.x)[q]) + iv*gv;
      (&cnew.x)[q] = cv;
      store_h(h0wr, blk, hi*4+q, u, ov*tanhx(cv));
    }
    *(float4*)cp = cnew;
  }
}

// ===================== k2: layer1 gates + cell =====================
__global__ __launch_bounds__(512, 1)
void k_layer1(const unsigned short* __restrict__ wsW,
              const unsigned short* __restrict__ h0n,
              const unsigned short* __restrict__ h1rd,
              unsigned short* __restrict__ h1wr,
              float* __restrict__ c1g,
              const float* __restrict__ bih1,
              const float* __restrict__ bhh1)
{
  const int tid  = threadIdx.x;
  const int lane = tid & 63;
  const int w    = tid >> 6;
  const int wb   = w >> 1;
  const int wh   = w & 1;
  const int col  = lane & 15;
  const int hi   = lane >> 4;
  const int bt   = blockIdx.x >> 3;
  const int sl   = blockIdx.x & 7;

  const int blk0 = bt*8 + wb*2;
  const int ut   = sl*2 + wh;
  const int u    = ut*16 + col;

  f32x4 acc[2][4];
  #pragma unroll
  for (int g=0;g<4;g++){
    int row = g*256 + u;
    float bv = bih1[row] + bhh1[row];
    #pragma unroll
    for (int q=0;q<4;q++){ acc[0][g][q] = bv; acc[1][g][q] = bv; }
  }

  #pragma unroll
  for (int kt=0;kt<8;kt++){
    s8v a0 = ld_af(h0n, blk0,   kt, lane);
    s8v a1 = ld_af(h0n, blk0+1, kt, lane);
    #pragma unroll
    for (int g=0;g<4;g++){
      const int r = (g*8 + kt)*16 + ut;
      s8v bf = *(const s8v*)(wsW + 262144 + (size_t)r*512 + lane*8);
      acc[0][g] = MFMA16(a0, bf, acc[0][g]);
      acc[1][g] = MFMA16(a1, bf, acc[1][g]);
    }
  }
  #pragma unroll
  for (int kt=0;kt<8;kt++){
    s8v a0 = ld_af(h1rd, blk0,   kt, lane);
    s8v a1 = ld_af(h1rd, blk0+1, kt, lane);
    #pragma unroll
    for (int g=0;g<4;g++){
      const int r = (g*8 + kt)*16 + ut;
      s8v bf = *(const s8v*)(wsW + 524288 + (size_t)r*512 + lane*8);
      acc[0][g] = MFMA16(a0, bf, acc[0][g]);
      acc[1][g] = MFMA16(a1, bf, acc[1][g]);
    }
  }

  #pragma unroll
  for (int m2=0;m2<2;m2++){
    const int blk = blk0 + m2;
    float* cp = c1g + (size_t)blk*4096 + u*16 + hi*4;
    float4 cold = *(const float4*)cp;
    float4 cnew;
    #pragma unroll
    for (int q=0;q<4;q++){
      float iv = sigm(acc[m2][0][q]);
      float fv = sigm(acc[m2][1][q]);
      float gv = tanhx(acc[m2][2][q]);
      float ov = sigm(acc[m2][3][q]);
      float cv = fv*((&cold.x)[q]) + iv*gv;
      (&cnew.x)[q] = cv;
      store_h(h1wr, blk, hi*4+q, u, ov*tanhx(cv));
    }
    *(float4*)cp = cnew;
  }
}

// ===================== k_head: final step's out only =====================
__global__ __launch_bounds__(256, 2)
void k_head(const unsigned short* __restrict__ wsW,
            const unsigned short* __restrict__ h1n,
            const float* __restrict__ posRd,
            const float* __restrict__ bp1,
            const float* __restrict__ Wp2,
            const float* __restrict__ bp2,
            float* __restrict__ out, int t)
{
  const int tid  = threadIdx.x;
  const int lane = tid & 63;
  const int w    = tid >> 6;
  const int col  = lane & 15;
  const int hi   = lane >> 4;
  const int bt   = blockIdx.x;

  float bpv[4], w2a[4], w2b[4];
  #pragma unroll
  for (int n=0;n<4;n++){
    bpv[n] = bp1[n*16 + col];
    w2a[n] = Wp2[n*16 + col];
    w2b[n] = Wp2[64 + n*16 + col];
  }
  const float bp20 = bp2[0], bp21 = bp2[1];

  #pragma unroll
  for (int m2=0;m2<2;m2++){
    const int blk = bt*8 + w*2 + m2;
    f32x4 acc[4];
    #pragma unroll
    for (int n=0;n<4;n++)
      #pragma unroll
      for (int q=0;q<4;q++) acc[n][q] = bpv[n];
    #pragma unroll
    for (int kt=0;kt<8;kt++){
      s8v a = ld_af(h1n, blk, kt, lane);
      #pragma unroll
      for (int n=0;n<4;n++){
        s8v bf = *(const s8v*)(wsW + 786432 + (size_t)(n*8+kt)*512 + lane*8);
        acc[n] = MFMA16(a, bf, acc[n]);
      }
    }
    #pragma unroll
    for (int q=0;q<4;q++){
      float s0 = 0.f, s1 = 0.f;
      #pragma unroll
      for (int n=0;n<4;n++){
        float r = fmaxf(acc[n][q], 0.f);
        s0 += r*w2a[n]; s1 += r*w2b[n];
      }
      #pragma unroll
      for (int off=1; off<16; off<<=1){
        s0 += __shfl_xor(s0, off, 64);
        s1 += __shfl_xor(s1, off, 64);
      }
      if (col == 0){
        int b = blk*16 + hi*4 + q;
        out[((size_t)b*NSTEP + t)*2]     = posRd[(size_t)b*2]     + s0 + bp20;
        out[((size_t)b*NSTEP + t)*2 + 1] = posRd[(size_t)b*2 + 1] + s1 + bp21;
      }
    }
  }
}

extern "C" void kernel_launch(void* const* d_in, const int* in_sizes, int n_in,
                              void* d_out, int out_size, void* d_ws, size_t ws_size,
                              hipStream_t stream) {
  const float* enc  = (const float*)d_in[0];
  const float* pos0 = (const float*)d_in[1];
  const float* ctx  = (const float*)d_in[2];
  const float* Wh   = (const float*)d_in[3];
  const float* bh   = (const float*)d_in[4];
  const float* Wc   = (const float*)d_in[5];
  const float* bc   = (const float*)d_in[6];
  const float* Wih0 = (const float*)d_in[7];
  const float* Whh0 = (const float*)d_in[8];
  const float* bih0 = (const float*)d_in[9];
  const float* bhh0 = (const float*)d_in[10];
  const float* Wih1 = (const float*)d_in[11];
  const float* Whh1 = (const float*)d_in[12];
  const float* bih1 = (const float*)d_in[13];
  const float* bhh1 = (const float*)d_in[14];
  const float* Wp1  = (const float*)d_in[15];
  const float* bp1  = (const float*)d_in[16];
  const float* Wp2  = (const float*)d_in[17];
  const float* bp2  = (const float*)d_in[18];
  float* out = (float*)d_out;
  unsigned short* wsW = (unsigned short*)d_ws;

  unsigned short* h0a = (unsigned short*)((char*)d_ws + H0A_OFF);
  unsigned short* h0b = (unsigned short*)((char*)d_ws + H0B_OFF);
  unsigned short* h1a = (unsigned short*)((char*)d_ws + H1A_OFF);
  unsigned short* h1b = (unsigned short*)((char*)d_ws + H1B_OFF);
  unsigned short* gxg = (unsigned short*)((char*)d_ws + GX_OFF);
  float* c0g  = (float*)((char*)d_ws + C0_OFF);
  float* c1g  = (float*)((char*)d_ws + C1_OFF);
  float* posA = (float*)((char*)d_ws + POSA_OFF);
  float* posB = (float*)((char*)d_ws + POSB_OFF);

  hipLaunchKernelGGL(repack, dim3(392), dim3(256), 0, stream,
                     Whh0, Wih1, Whh1, Wp1, wsW);

  hipLaunchKernelGGL(k_init, dim3(256), dim3(512), 0, stream,
                     enc, pos0, ctx, Wh, bh, Wc, bc, Wih0, bih0, bhh0,
                     h0a, h1a, gxg, c0g, c1g, posA);

  unsigned short* h1prev = h1a;
  for (int t = 0; t < NSTEP; t++){
    unsigned short* h0r = (t & 1) ? h0b : h0a;
    unsigned short* h0w = (t & 1) ? h0a : h0b;
    unsigned short* h1r = (t & 1) ? h1b : h1a;
    unsigned short* h1w = (t & 1) ? h1a : h1b;
    float* posRead  = (t == 0) ? posA : ((t & 1) ? posA : posB); // pos_{t-1}
    float* posWrite = (t & 1) ? posB : posA;                     // pos_t

    hipLaunchKernelGGL(k_layer0, dim3(256), dim3(512), 0, stream,
                       wsW, gxg, h0r, h0w, h1prev, c0g,
                       posRead, posWrite, Wih0, bp1, Wp2, bp2, out, t);
    hipLaunchKernelGGL(k_layer1, dim3(256), dim3(512), 0, stream,
                       wsW, h0w, h1r, h1w, c1g, bih1, bhh1);
    h1prev = h1w;
  }
  hipLaunchKernelGGL(k_head, dim3(32), dim3(256), 0, stream,
                     wsW, h1prev, posA, bp1, Wp2, bp2, out, NSTEP-1);
}